// Round 13
// baseline (281.318 us; speedup 1.0000x reference)
//
#include <hip/hip_runtime.h>
#include <math.h>

// Problem constants (fixed by setup_inputs)
#define NB 2
#define NL 2048
#define NH 16
#define ND 64
#define NDM 1024
#define NU 409                  // max(1, 2048 // 5)
#define NUP 416                 // NU padded to multiple of 32; 416 = 26*16 = 13*32
#define NBH (NB*NH)             // 32
#define NROWS (NB*NL)           // 4096
#define NRTOT (NB*NH*NL)        // 65536
#define MTOT (NBH*NUP)          // 13312

typedef short bf16x8 __attribute__((ext_vector_type(8)));
typedef short bf16x4 __attribute__((ext_vector_type(4)));
typedef float f32x4  __attribute__((ext_vector_type(4)));

__device__ __forceinline__ short f2bf(float x) {   // RNE f32 -> bf16
  unsigned u = __float_as_uint(x);
  return (short)((u + 0x7FFFu + ((u >> 16) & 1u)) >> 16);
}
__device__ __forceinline__ float bf2f(short s) {
  return __uint_as_float(((unsigned)(unsigned short)s) << 16);
}

__device__ __forceinline__ void gload16(const short* g, short* l) {
  __builtin_amdgcn_global_load_lds(
      (const __attribute__((address_space(1))) void*)g,
      (__attribute__((address_space(3))) void*)l, 16, 0, 0);
}

// ---------------------------------------------------------------- multi-tensor f32 -> bf16 splits
struct SplitDesc { const float* in; short* a; short* b; short* c; int nc; int nblk; };
struct SplitArgs { SplitDesc d[7]; };

__global__ __launch_bounds__(256) void msplit_k(SplitArgs args) {
  const SplitDesc d = args.d[blockIdx.z];
  if ((int)blockIdx.x >= d.nblk) return;
  const size_t i = (size_t)blockIdx.x * 256 + threadIdx.x;
  const float4 x0 = ((const float4*)d.in)[2*i];
  const float4 x1 = ((const float4*)d.in)[2*i + 1];
  float x[8] = {x0.x,x0.y,x0.z,x0.w, x1.x,x1.y,x1.z,x1.w};
  bf16x8 va, vb, vc;
  #pragma unroll
  for (int j = 0; j < 8; ++j) {
    const short A = f2bf(x[j]);
    const float r1 = x[j] - bf2f(A);
    const short B = f2bf(r1);
    va[j] = A; vb[j] = B;
    vc[j] = f2bf(r1 - bf2f(B));
  }
  *(bf16x8*)(d.a + 8*i) = va;
  if (d.nc >= 2) *(bf16x8*)(d.b + 8*i) = vb;
  if (d.nc == 3) *(bf16x8*)(d.c + 8*i) = vc;
}

// ---------------------------------------------------------------- 8-phase 256x256 mega GEMM (Q/K0/K1/V)
// BM=BN=256, BK=64, 512 thr (8 waves 2Mx4N); wave covers 128m x 64n = 8x4 frags.
// LDS 128 KiB: 2 bufs x {A-half0,A-half1,B-half0,B-half1} x 16 KiB.
// chunk pairs (c=step>>4): c0 (a,a), c1 (a,b), c2 (b,a), c3 (a,c), c4 (c,a), c5 (b,b)
// Staging: linear LDS dest (global_load_lds), pre-swizzled global k-slot
// s^=(row&7); frag ds_read applies the same XOR (rule 21).
// Per tile-pair (i,i+1): 8 phases, each {ds_read frags; stage 1 half-tile;
// raw barrier; setprio; 16 MFMA; setprio; barrier}. Stage order:
// ph1:A0(i+1) ph2:A1(i+1) ph3:B0(i+2) ph4:B1(i+2) ph5:A0(i+2) ph6:A1(i+2)
// ph7:B0(i+3) ph8:B1(i+3). Counted s_waitcnt vmcnt(2) at ph4/ph8 (pre-stage),
// never 0 in the loop (T4). Prologue: 6 half-tiles then vmcnt(4)+barrier.
struct G8Desc {
  const short* X[3];
  const short* W[3];
  const float* bias;   // modes 0,2
  float* C;            // modes 0/1
  short* Vt;           // mode 2
  int sbeg, send, mode;
};
struct G8Args { G8Desc d[4]; };

__device__ __forceinline__ void g8_stage(const G8Desc& d, int T, int t, int ht,
                                         int m0, int n0, int srow, int ssw,
                                         short* LDS, int tid) {
  if (t >= T) return;
  const int g = d.sbeg + t;
  const int c = g >> 4, kk = (g & 15) << 6;
  const short *Xg, *Wg;
  switch (c) {
    case 0:  Xg = d.X[0]; Wg = d.W[0]; break;
    case 1:  Xg = d.X[0]; Wg = d.W[1]; break;
    case 2:  Xg = d.X[1]; Wg = d.W[0]; break;
    case 3:  Xg = d.X[0]; Wg = d.W[2]; break;
    case 4:  Xg = d.X[2]; Wg = d.W[0]; break;
    default: Xg = d.X[1]; Wg = d.W[1]; break;
  }
  const short* src = (ht < 2) ? Xg : Wg;
  const int rb = ((ht < 2) ? m0 : n0) + ((ht & 1) << 7) + srow;
  const size_t off = (size_t)rb * NDM + kk + ssw;
  short* dsl = LDS + ((t & 1) << 15) + (ht << 13) + (tid << 3);
  gload16(src + off, dsl);
  gload16(src + off + ((size_t)64 * NDM), dsl + 4096);
}

template<int PP>
__device__ __forceinline__ void g8_phase(
    const G8Desc& d, int T, short* LDS, int bufo,
    int abase0, int bbase0, int lg, int asw,
    int stT, int stH, int m0, int n0, int srow, int ssw, int tid,
    f32x4 (&acc)[8][4], bf16x8 (&bfr)[4][2])
{
  if (PP == 0) {
    #pragma unroll
    for (int nf = 0; nf < 4; ++nf)
      #pragma unroll
      for (int kh = 0; kh < 2; ++kh)
        bfr[nf][kh] = *(const bf16x8*)(LDS + bufo + bbase0 + nf*1024 +
                                       ((((kh << 2) + lg) ^ asw) << 3));
  }
  bf16x8 af[2][2];
  #pragma unroll
  for (int m2 = 0; m2 < 2; ++m2)
    #pragma unroll
    for (int kh = 0; kh < 2; ++kh)
      af[m2][kh] = *(const bf16x8*)(LDS + bufo + abase0 + (PP*2 + m2)*1024 +
                                    ((((kh << 2) + lg) ^ asw) << 3));
  if (PP == 3) asm volatile("s_waitcnt vmcnt(2)" ::: "memory");
  g8_stage(d, T, stT, stH, m0, n0, srow, ssw, LDS, tid);
  asm volatile("" ::: "memory");
  __builtin_amdgcn_s_barrier();
  asm volatile("" ::: "memory");
  __builtin_amdgcn_s_setprio(1);
  #pragma unroll
  for (int m2 = 0; m2 < 2; ++m2)
    #pragma unroll
    for (int nf = 0; nf < 4; ++nf)
      #pragma unroll
      for (int kh = 0; kh < 2; ++kh)
        acc[PP*2 + m2][nf] = __builtin_amdgcn_mfma_f32_16x16x32_bf16(
            bfr[nf][kh], af[m2][kh], acc[PP*2 + m2][nf], 0, 0, 0);
  __builtin_amdgcn_s_setprio(0);
  asm volatile("" ::: "memory");
  __builtin_amdgcn_s_barrier();
  asm volatile("" ::: "memory");
}

__global__ __launch_bounds__(512, 2) void gemm8_k(G8Args args) {
  __shared__ short LDS[65536];   // 128 KiB
  const int fid = blockIdx.x;
  const int s = fid & 3, tile = fid >> 2;
  const int bx = tile & 3, by = tile >> 2;
  const G8Desc d = args.d[s];
  const int tid = threadIdx.x;
  const int w = tid >> 6, L = tid & 63;
  const int lr = L & 15, lg = L >> 4;
  const int n0 = bx << 8, m0 = by << 8;
  const int wmh = w >> 2;                 // A-half of this wave
  const int wn = (w & 3) << 6;
  const int T = d.send - d.sbeg;
  const int srow = tid >> 3;
  const int ssw = ((tid & 7) ^ (srow & 7)) << 3;
  const int asw = lr & 7;
  const int abase0 = wmh*8192 + lr*64;
  const int bbase0 = 16384 + ((w & 3) >> 1)*8192 + ((wn & 64) + lr)*64;

  f32x4 acc[8][4];
  #pragma unroll
  for (int i = 0; i < 8; ++i)
    #pragma unroll
    for (int j = 0; j < 4; ++j) acc[i][j] = (f32x4){0.f,0.f,0.f,0.f};
  bf16x8 bfr[4][2];

  // ---- prologue: B(0), A(0), B(1); then wait tile 0 landed
  g8_stage(d, T, 0, 2, m0, n0, srow, ssw, LDS, tid);
  g8_stage(d, T, 0, 3, m0, n0, srow, ssw, LDS, tid);
  g8_stage(d, T, 0, 0, m0, n0, srow, ssw, LDS, tid);
  g8_stage(d, T, 0, 1, m0, n0, srow, ssw, LDS, tid);
  g8_stage(d, T, 1, 2, m0, n0, srow, ssw, LDS, tid);
  g8_stage(d, T, 1, 3, m0, n0, srow, ssw, LDS, tid);
  asm volatile("s_waitcnt vmcnt(4)" ::: "memory");
  __builtin_amdgcn_s_barrier();
  asm volatile("" ::: "memory");

  for (int i = 0; i < T; i += 2) {
    // tile i (buf 0)
    g8_phase<0>(d, T, LDS, 0,     abase0, bbase0, lg, asw, i+1, 0, m0, n0, srow, ssw, tid, acc, bfr);
    g8_phase<1>(d, T, LDS, 0,     abase0, bbase0, lg, asw, i+1, 1, m0, n0, srow, ssw, tid, acc, bfr);
    g8_phase<2>(d, T, LDS, 0,     abase0, bbase0, lg, asw, i+2, 2, m0, n0, srow, ssw, tid, acc, bfr);
    g8_phase<3>(d, T, LDS, 0,     abase0, bbase0, lg, asw, i+2, 3, m0, n0, srow, ssw, tid, acc, bfr);
    // tile i+1 (buf 1)
    g8_phase<0>(d, T, LDS, 32768, abase0, bbase0, lg, asw, i+2, 0, m0, n0, srow, ssw, tid, acc, bfr);
    g8_phase<1>(d, T, LDS, 32768, abase0, bbase0, lg, asw, i+2, 1, m0, n0, srow, ssw, tid, acc, bfr);
    g8_phase<2>(d, T, LDS, 32768, abase0, bbase0, lg, asw, i+3, 2, m0, n0, srow, ssw, tid, acc, bfr);
    g8_phase<3>(d, T, LDS, 32768, abase0, bbase0, lg, asw, i+3, 3, m0, n0, srow, ssw, tid, acc, bfr);
  }

  const int wm = wmh << 7;
  if (d.mode == 2) {
    // fused V epilogue: +bias, transposed bf16 scalar stores into Vt[bh][d][l]
    #pragma unroll
    for (int nf = 0; nf < 4; ++nf) {
      const int n = n0 + wn + (nf << 4) + (lg << 2);
      const float4 b4 = *(const float4*)(d.bias + n);
      const int h = n >> 6, db = n & 63;
      #pragma unroll
      for (int mf = 0; mf < 8; ++mf) {
        const int m = m0 + wm + (mf << 4) + lr;
        const int bb = m >> 11, ll = m & (NL - 1);
        short* vt = d.Vt + (((size_t)((((bb << 4) + h) << 6) + db)) << 11) + ll;
        vt[0]    = f2bf(acc[mf][nf][0] + b4.x);
        vt[2048] = f2bf(acc[mf][nf][1] + b4.y);
        vt[4096] = f2bf(acc[mf][nf][2] + b4.z);
        vt[6144] = f2bf(acc[mf][nf][3] + b4.w);
      }
    }
  } else {
    #pragma unroll
    for (int nf = 0; nf < 4; ++nf) {
      const int n = n0 + wn + (nf << 4) + (lg << 2);
      float4 b4 = make_float4(0.f, 0.f, 0.f, 0.f);
      if (d.mode == 0) b4 = *(const float4*)(d.bias + n);
      const int hh = n >> 6, dd = n & 63;
      #pragma unroll
      for (int mf = 0; mf < 8; ++mf) {
        f32x4 a = acc[mf][nf];
        a[0] += b4.x; a[1] += b4.y; a[2] += b4.z; a[3] += b4.w;
        const int m = m0 + wm + (mf << 4) + lr;
        const int bb = m >> 11, ll = m & (NL - 1);
        *(f32x4*)(d.C + (((size_t)(bb*NH + hh)*NL + ll) << 6) + dd) = a;
      }
    }
  }
}

// ---------------------------------------------------------------- K combine: Kp0+Kp1+bias -> Kbf bf16, khat partials
__global__ __launch_bounds__(256) void combine_k(const float* __restrict__ Kp0,
                                                 const float* __restrict__ Kp1,
                                                 const float* __restrict__ bk,
                                                 short* __restrict__ Kbf,
                                                 double* __restrict__ kpart) {
  __shared__ double sm[4][64];
  const int bh = blockIdx.x >> 5, seg = blockIdx.x & 31;
  const int g = threadIdx.x >> 6, d = threadIdx.x & 63;
  const int h = bh & 15;
  const float bias = bk[(h << 6) + d];
  double acc = 0.0;
  #pragma unroll 4
  for (int i = 0; i < 16; ++i) {
    const int l = (seg << 6) + (i << 2) + g;
    const size_t o = (((size_t)bh * NL + l) << 6) + d;
    const float k = Kp0[o] + Kp1[o] + bias;
    float ss = k * k;
    #pragma unroll
    for (int off = 32; off > 0; off >>= 1) ss += __shfl_xor(ss, off);
    const double inv = 1.0 / sqrt((double)ss);
    Kbf[o] = f2bf(k);
    acc += (double)k * inv;
  }
  sm[g][d] = acc;
  __syncthreads();
  if (threadIdx.x < 64)
    kpart[((((size_t)bh << 5) + seg) << 6) + threadIdx.x] =
        sm[0][threadIdx.x] + sm[1][threadIdx.x] + sm[2][threadIdx.x] + sm[3][threadIdx.x];
}

// ---------------------------------------------------------------- wtilde (+inline kbar reduce): wt[bh][j] f32, s0[bh] f64
__global__ __launch_bounds__(256) void wtilde_k(const float* __restrict__ Wq,
                                                const float* __restrict__ bq,
                                                const double* __restrict__ kpart,
                                                float* __restrict__ wt,
                                                double* __restrict__ s0) {
  __shared__ double kb[64];
  const int bh = blockIdx.x, h = bh & 15;
  const int tid = threadIdx.x;
  if (tid < 64) {
    double s = 0.0;
    #pragma unroll
    for (int seg = 0; seg < 32; ++seg)
      s += kpart[((((size_t)bh << 5) + seg) << 6) + tid];
    kb[tid] = s * (1.0 / NL);
  }
  __syncthreads();
  const int j = (blockIdx.y << 8) + tid;
  double a = 0.0;
  #pragma unroll 8
  for (int d = 0; d < 64; ++d)
    a += (double)Wq[(((size_t)((h << 6) + d)) << 10) + j] * kb[d];
  wt[((size_t)bh << 10) + j] = (float)a;
  if (blockIdx.y == 0 && tid < 64) {
    double p = (double)bq[(h << 6) + tid] * kb[tid];
    #pragma unroll
    for (int off = 32; off > 0; off >>= 1) p += __shfl_xor(p, off);
    if (tid == 0) s0[bh] = p;
  }
}

// ---------------------------------------------------------------- fused dotq+msq: ms[bh][l] = (x.wt + s0)/|q|
__global__ __launch_bounds__(256) void dotqms_k(const float* __restrict__ x,
                                                const float* __restrict__ Qb,
                                                const float* __restrict__ wt,
                                                const double* __restrict__ s0,
                                                float* __restrict__ ms) {
  __shared__ float xs[1024];
  __shared__ double sm[16][16];
  __shared__ double sq[16][16];
  const int r = blockIdx.x, b = r >> 11, l = r & (NL - 1);
  const int tid = threadIdx.x;
  ((float4*)xs)[tid] = ((const float4*)(x + ((size_t)r << 10)))[tid];
  __syncthreads();
  const int h = tid >> 4, t = tid & 15;
  const float* w = wt + ((size_t)((b << 4) + h) << 10);
  double a = 0.0;
  #pragma unroll 8
  for (int i = 0; i < 64; ++i) {
    const int j = t + (i << 4);
    a += (double)xs[j] * (double)w[j];
  }
  sm[h][t] = a;
  const float4 qv = *(const float4*)(Qb + (((size_t)((b << 4) + h) * NL + l) << 6) + (t << 2));
  sq[h][t] = (double)qv.x*qv.x + (double)qv.y*qv.y + (double)qv.z*qv.z + (double)qv.w*qv.w;
  __syncthreads();
  if (tid < 16) {
    double s = 0.0, ssq = 0.0;
    #pragma unroll
    for (int t2 = 0; t2 < 16; ++t2) { s += sm[tid][t2]; ssq += sq[tid][t2]; }
    ms[(((size_t)(b << 4) + tid) << 11) + l] = (float)((s + s0[(b << 4) + tid]) / sqrt(ssq));
  }
}

// ---------------------------------------------------------------- rank-based top-NU selection (+ inverse map; pad -> NU)
__global__ __launch_bounds__(256) void select_rank_k(const float* __restrict__ ms,
                                                     int* __restrict__ sel,
                                                     int* __restrict__ invsel) {
  __shared__ unsigned long long keys[NL];
  const int bh = blockIdx.x >> 3, seg = blockIdx.x & 7;
  const int tid = threadIdx.x;
  for (int l = tid; l < NL; l += 256) {
    unsigned u = __float_as_uint(ms[(size_t)bh * NL + l]);
    u = (u & 0x80000000u) ? ~u : (u | 0x80000000u);   // order-preserving map
    keys[l] = ((unsigned long long)u << 32) | (unsigned)(NL - 1 - l);
  }
  __syncthreads();
  const int r = (seg << 8) + tid;
  const unsigned long long mine = keys[r];
  int cnt = 0;
  #pragma unroll 8
  for (int l = 0; l < NL; ++l) cnt += (keys[l] > mine) ? 1 : 0;
  if (cnt < NU) sel[bh*NU + cnt] = r;
  invsel[(size_t)bh * NL + r] = (cnt < NU) ? cnt : NU;  // NU = zeroed pad row
}

// ---------------------------------------------------------------- fused attention with inline Q gather; split bf16 Csel out
__global__ __launch_bounds__(512) void fattn_k(const float* __restrict__ Qb,
                                               const int* __restrict__ sel,
                                               const short* __restrict__ Kbf,
                                               const short* __restrict__ Vt,
                                               short* __restrict__ Ca,
                                               short* __restrict__ Cb) {
  __shared__ short S[32*2048];        // 128 KB, row stride 4096 B
  __shared__ float inv_s[32];
  int bid = blockIdx.x;
  bid = (bid & 7) * 52 + (bid >> 3);  // 416 = 8*52 XCD chunks
  const int m0 = bid << 5;
  const int bh = m0 / NUP;
  const int u0 = m0 - bh * NUP;
  const int tid = threadIdx.x;
  const int w = tid >> 6, L = tid & 63;
  const int lr = L & 15, lg = L >> 4;

  // ---- Q fragments gathered from f32 Qb via sel (pad rows read row 0, discarded)
  bf16x8 qf[2][2];
  #pragma unroll
  for (int mt = 0; mt < 2; ++mt) {
    const int u = u0 + mt*16 + lr;
    const int lq = (u < NU) ? sel[bh*NU + u] : 0;
    const float* qp = Qb + (((size_t)bh*NL + lq) << 6) + lg*8;
    const float4 q0 = *(const float4*)qp;
    const float4 q1 = *(const float4*)(qp + 4);
    const float4 q2 = *(const float4*)(qp + 32);
    const float4 q3 = *(const float4*)(qp + 36);
    qf[mt][0][0]=f2bf(q0.x); qf[mt][0][1]=f2bf(q0.y); qf[mt][0][2]=f2bf(q0.z); qf[mt][0][3]=f2bf(q0.w);
    qf[mt][0][4]=f2bf(q1.x); qf[mt][0][5]=f2bf(q1.y); qf[mt][0][6]=f2bf(q1.z); qf[mt][0][7]=f2bf(q1.w);
    qf[mt][1][0]=f2bf(q2.x); qf[mt][1][1]=f2bf(q2.y); qf[mt][1][2]=f2bf(q2.z); qf[mt][1][3]=f2bf(q2.w);
    qf[mt][1][4]=f2bf(q3.x); qf[mt][1][5]=f2bf(q3.y); qf[mt][1][6]=f2bf(q3.z); qf[mt][1][7]=f2bf(q3.w);
  }
  const int nb = w << 8;
  const short* kb0 = Kbf + (((size_t)bh*NL + nb + lr) << 6) + lg*8;
  #pragma unroll 2
  for (int nt = 0; nt < 16; ++nt) {
    const short* kp = kb0 + ((size_t)nt << 10);
    const bf16x8 kf0 = *(const bf16x8*)kp;
    const bf16x8 kf1 = *(const bf16x8*)(kp + 32);
    #pragma unroll
    for (int mt = 0; mt < 2; ++mt) {
      f32x4 a = {0.f,0.f,0.f,0.f};
      a = __builtin_amdgcn_mfma_f32_16x16x32_bf16(kf0, qf[mt][0], a, 0, 0, 0);
      a = __builtin_amdgcn_mfma_f32_16x16x32_bf16(kf1, qf[mt][1], a, 0, 0, 0);
      const int m = mt*16 + lr;
      bf16x4 o;
      #pragma unroll
      for (int r = 0; r < 4; ++r) o[r] = f2bf(a[r] * 0.125f);
      const int byteoff = (m << 12) + ((((nb + nt*16 + lg*4) << 1)) ^ ((m & 7) << 4));
      *(bf16x4*)((char*)S + byteoff) = o;
    }
  }
  __syncthreads();

  #pragma unroll
  for (int j = 0; j < 4; ++j) {
    const int R = (w << 2) + j;
    char* rowp = (char*)S + (R << 12);
    const int sw = (R & 7) << 4;
    bf16x8 v[4];
    #pragma unroll
    for (int i = 0; i < 4; ++i)
      v[i] = *(const bf16x8*)(rowp + (((L << 6) + (i << 4)) ^ sw));
    float f[32];
    #pragma unroll
    for (int i = 0; i < 4; ++i)
      #pragma unroll
      for (int e = 0; e < 8; ++e) f[i*8+e] = bf2f(v[i][e]);
    float mx = f[0];
    #pragma unroll
    for (int i = 1; i < 32; ++i) mx = fmaxf(mx, f[i]);
    #pragma unroll
    for (int off = 32; off > 0; off >>= 1) mx = fmaxf(mx, __shfl_xor(mx, off));
    float sum = 0.f;
    #pragma unroll
    for (int i = 0; i < 32; ++i) { f[i] = __expf(f[i] - mx); sum += f[i]; }
    #pragma unroll
    for (int off = 32; off > 0; off >>= 1) sum += __shfl_xor(sum, off);
    bf16x8 p[4];
    #pragma unroll
    for (int i = 0; i < 4; ++i)
      #pragma unroll
      for (int e = 0; e < 8; ++e) p[i][e] = f2bf(f[i*8+e]);
    #pragma unroll
    for (int i = 0; i < 4; ++i)
      *(bf16x8*)(rowp + (((L << 6) + (i << 4)) ^ sw)) = p[i];
    if (L == 0) inv_s[R] = 1.f / sum;
  }
  __syncthreads();

  {
    const int mt = w & 1, dt = w >> 1;
    const int m = mt*16 + lr;
    const char* arow = (const char*)S + (m << 12);
    const int sw = (m & 7) << 4;
    const short* vrow = Vt + (((size_t)bh*ND + dt*16 + lr) << 11) + lg*8;
    f32x4 acc0 = {0.f,0.f,0.f,0.f}, acc1 = {0.f,0.f,0.f,0.f};
    for (int k0 = 0; k0 < NL; k0 += 64) {
      const bf16x8 p0 = *(const bf16x8*)(arow + ((((k0 + lg*8) << 1)) ^ sw));
      const bf16x8 p1 = *(const bf16x8*)(arow + ((((k0 + 32 + lg*8) << 1)) ^ sw));
      const bf16x8 v0 = *(const bf16x8*)(vrow + k0);
      const bf16x8 v1 = *(const bf16x8*)(vrow + k0 + 32);
      acc0 = __builtin_amdgcn_mfma_f32_16x16x32_bf16(p0, v0, acc0, 0, 0, 0);
      acc1 = __builtin_amdgcn_mfma_f32_16x16x32_bf16(p1, v1, acc1, 0, 0, 0);
    }
    const int ub = u0 + mt*16 + (lg << 2);
    #pragma unroll
    for (int r = 0; r < 4; ++r) {
      float val = (acc0[r] + acc1[r]) * inv_s[mt*16 + (lg << 2) + r];
      if (ub + r >= NU) val = 0.f;                 // zero pad rows (incl. row NU)
      const size_t off = (((size_t)m0 + mt*16 + (lg << 2) + r) << 6) + dt*16 + lr;
      const short A = f2bf(val);
      Ca[off] = A;
      Cb[off] = f2bf(val - bf2f(A));
    }
  }
}

// ---------------------------------------------------------------- O projection GEMM (X gathered from Csel via invsel)
// 768 blocks; split-K 3-way interleaved per CU (3 blocks/CU). Full 128x128 tile.
struct OselArgs {
  const short* Xa; const short* Xb;
  const short* Wa; const short* Wb;
  float* C0; float* C1; float* C2;   // thirds: steps [0,16) [16,32) [32,48)
  const int* invsel;
};

__global__ __launch_bounds__(256, 3) void gemm_osel_k(OselArgs ar) {
  __shared__ short As[128*64];   // 16 KB
  __shared__ short Bs[128*64];   // 16 KB
  __shared__ int utbl[2048];     // 8 KB
  const int fid = blockIdx.x;
  const int xcd = fid & 7, jd = fid >> 3;   // jd 0..95
  const int zi = jd % 3;
  const int o = (xcd << 5) + (jd / 3);      // 0..255
  const int bx = o & 7, by = o >> 3;
  const int sbeg = zi << 4, send = sbeg + 16;
  float* C = (zi == 0) ? ar.C0 : (zi == 1) ? ar.C1 : ar.C2;
  const int tid = threadIdx.x;
  const int wv = tid >> 6, L = tid & 63;
  const int lr = L & 15, lg = L >> 4;
  const int n0 = bx << 7, m0 = by << 7;
  const int wm = (wv >> 1) << 6, wn = (wv & 1) << 6;
  const int sr = tid >> 3, ssl = tid & 7;
  const int b2 = by >> 4;

  #pragma unroll
  for (int e = 0; e < 8; ++e) {
    const int idx = (tid << 3) + e;             // 0..2047
    const int row = idx >> 4, h = idx & 15;
    utbl[idx] = ar.invsel[((((size_t)b2 << 4) + h) << 11) + ((m0 + row) & (NL - 1))];
  }
  __syncthreads();

  f32x4 acc[4][4];
  #pragma unroll
  for (int i = 0; i < 4; ++i)
    #pragma unroll
    for (int j = 0; j < 4; ++j) acc[i][j] = (f32x4){0.f,0.f,0.f,0.f};

  for (int step = sbeg; step < send; ++step) {
    const int c = step >> 4, kk = (step & 15) << 6;
    const short* Wg = (c == 1) ? ar.Wb : ar.Wa;   // c0:(a,a) c1:(a,b) c2:(b,a)
    const short* Xs = (c == 2) ? ar.Xb : ar.Xa;
    #pragma unroll
    for (int j = 0; j < 4; ++j) {
      const int row = (j << 5) + sr;
      const int slot = (ssl ^ (row & 7)) << 3;
      const int h = step & 15;                  // one head per 64-wide step
      const int u = utbl[(row << 4) + h];
      gload16(Xs + (((size_t)((b2 << 4) + h) * NUP + u) << 6) + slot,
              As + (j << 11) + (tid << 3));
      gload16(Wg + (size_t)(n0 + row) * NDM + kk + slot, Bs + (j << 11) + (tid << 3));
    }
    __syncthreads();
    #pragma unroll
    for (int c2 = 0; c2 < 2; ++c2) {
      const int sl = (((c2 << 2) + lg) ^ (lr & 7)) << 3;
      bf16x8 af[4], bfr[4];
      #pragma unroll
      for (int t = 0; t < 4; ++t) {
        af[t]  = *(const bf16x8*)(As + ((wm + (t << 4) + lr) << 6) + sl);
        bfr[t] = *(const bf16x8*)(Bs + ((wn + (t << 4) + lr) << 6) + sl);
      }
      #pragma unroll
      for (int mt = 0; mt < 4; ++mt)
        #pragma unroll
        for (int nt = 0; nt < 4; ++nt)
          acc[mt][nt] = __builtin_amdgcn_mfma_f32_16x16x32_bf16(bfr[nt], af[mt], acc[mt][nt], 0, 0, 0);
    }
    __syncthreads();
  }

  #pragma unroll
  for (int nt = 0; nt < 4; ++nt) {
    const int n = n0 + wn + (nt << 4) + (lg << 2);
    #pragma unroll
    for (int mt = 0; mt < 4; ++mt) {
      const int m = m0 + wm + (mt << 4) + lr;
      *(f32x4*)(C + ((size_t)m << 10) + n) = acc[mt][nt];
    }
  }
}

// ---------------------------------------------------------------- out += P1 + P2 + bias
__global__ __launch_bounds__(256) void oadd_k(float* __restrict__ out,
                                              const float* __restrict__ P1,
                                              const float* __restrict__ P2,
                                              const float* __restrict__ bo) {
  const size_t i4 = (size_t)blockIdx.x * 256 + threadIdx.x;
  const size_t i = i4 << 2;
  float4 a = *(float4*)(out + i);
  const float4 b = *(const float4*)(P1 + i);
  const float4 c = *(const float4*)(P2 + i);
  const float4 d = *(const float4*)(bo + ((i4 & 255) << 2));
  a.x += b.x + c.x + d.x; a.y += b.y + c.y + d.y;
  a.z += b.z + c.z + d.z; a.w += b.w + c.w + d.w;
  *(float4*)(out + i) = a;
}

// ---------------------------------------------------------------- launch
extern "C" void kernel_launch(void* const* d_in, const int* in_sizes, int n_in,
                              void* d_out, int out_size, void* d_ws, size_t ws_size,
                              hipStream_t stream)
{
  (void)in_sizes; (void)n_in; (void)out_size; (void)ws_size;
  const float* queries = (const float*)d_in[0];
  const float* keys    = (const float*)d_in[1];
  const float* values  = (const float*)d_in[2];
  const float* Wq = (const float*)d_in[3];  const float* bq = (const float*)d_in[4];
  const float* Wk = (const float*)d_in[5];  const float* bk = (const float*)d_in[6];
  const float* Wv = (const float*)d_in[7];  const float* bv = (const float*)d_in[8];
  const float* Wo = (const float*)d_in[9];  const float* bo = (const float*)d_in[10];
  float* out = (float*)d_out;

  char* base = (char*)d_ws;
  #define MB(x) ((size_t)(x) << 20)

  short* Qa   = (short*)(base + MB(0));    // queries split a (dead after mega)
  short* Qb2  = (short*)(base + MB(8));    // queries split b (dead after mega)
  short* Ka   = (short*)(base + MB(16));   // -> P2 (osel partial) after mega
  short* Kb2  = (short*)(base + MB(24));
  short* Kc   = (short*)(base + MB(32));   // -> Kbf after mega (combine_k writes)
  short* Vbf  = (short*)(base + MB(40));   // -> CselA/CselB after mega
  float* Qb   = (float*)(base + MB(48));   // Q proj f32 -> P1o after fattn
  short* Vt   = (short*)(base + MB(64));   // written during mega (mode-2 epilogue)
  short* Wqa  = (short*)(base + MB(72));
  short* Wqb  = (short*)(base + MB(74));
  short* Wka  = (short*)(base + MB(76));
  short* Wkb  = (short*)(base + MB(78));
  short* Wkc  = (short*)(base + MB(80));
  short* Wvbf = (short*)(base + MB(82));
  short* Woa  = (short*)(base + MB(84));
  short* Wob  = (short*)(base + MB(86));
  char* sm = base + MB(88);
  double* kpart  = (double*)sm;  sm += 524288;    // [32][32][64] f64
  float*  wt     = (float*)sm;   sm += 131072;    // [32][1024] f32
  double* s0     = (double*)sm;  sm += 512;
  float*  msb    = (float*)sm;   sm += 262144;
  int*    sel    = (int*)sm;     sm += 65536;
  int*    invsel = (int*)sm;     sm += 262144;
  float* Kp1 = (float*)(base + MB(90));    // 16 MiB K split-K partial 1

  // time-multiplexed aliases
  float* Kp0   = out;                       // K split-K partial 0 (out dead until osel)
  short* Kbf   = Kc;                        // written by combine_k after mega
  short* CselA = Vbf;                       // 1.625 MiB
  short* CselB = (short*)(base + MB(42));   // 1.625 MiB
  float* P1o   = Qb;                        // after fattn
  float* P2o   = (float*)Ka;                // 16 MiB (Ka+Kb2 region, dead after mega)

  // ---- 1: all splits in one launch (inputs + weights)
  {
    SplitArgs a;
    a.d[0] = {queries, Qa, Qb2, nullptr, 2, 2048};
    a.d[1] = {keys,    Ka, Kb2, Kc,      3, 2048};
    a.d[2] = {values,  Vbf, nullptr, nullptr, 1, 2048};
    a.d[3] = {Wq, Wqa, Wqb, nullptr, 2, 512};
    a.d[4] = {Wk, Wka, Wkb, Wkc,     3, 512};
    a.d[5] = {Wv, Wvbf, nullptr, nullptr, 1, 512};
    a.d[6] = {Wo, Woa, Wob, nullptr, 2, 512};
    msplit_k<<<dim3(2048,1,7), 256, 0, stream>>>(a);
  }
  // ---- 2: 8-phase 256^2 mega GEMM: Q(48) + K0(0..48->Kp0) + K1(48..96->Kp1)
  //         + V(16, fused transpose epilogue); 256 blocks x 512 threads
  {
    G8Args g;
    g.d[0] = {{Qa,Qb2,Qa},   {Wqa,Wqb,Wqa},    bq, Qb,  nullptr, 0, 48, 0};
    g.d[1] = {{Ka,Kb2,Kc},   {Wka,Wkb,Wkc},    nullptr, Kp0, nullptr, 0, 48, 1};
    g.d[2] = {{Ka,Kb2,Kc},   {Wka,Wkb,Wkc},    nullptr, Kp1, nullptr, 48, 96, 1};
    g.d[3] = {{Vbf,Vbf,Vbf}, {Wvbf,Wvbf,Wvbf}, bv, nullptr, Vt, 0, 16, 2};
    gemm8_k<<<256, 512, 0, stream>>>(g);
  }
  // ---- 3-6: K combine + ranking chain
  combine_k<<<NBH*32, 256, 0, stream>>>(Kp0, Kp1, bk, Kbf, kpart);
  wtilde_k<<<dim3(NBH,4), 256, 0, stream>>>(Wq, bq, kpart, wt, s0);
  dotqms_k<<<NROWS, 256, 0, stream>>>(queries, Qb, wt, s0, msb);
  select_rank_k<<<NBH*8, 256, 0, stream>>>(msb, sel, invsel);

  // ---- 7: fused attention (inline Q gather; split bf16 Csel; pad rows zeroed)
  fattn_k<<<MTOT/32, 512, 0, stream>>>(Qb, sel, Kbf, Vt, CselA, CselB);

  // ---- 8: output projection (X gathered from Csel via invsel), split-K 3-way
  {
    OselArgs oa = {CselA, CselB, Woa, Wob, out, P1o, P2o, invsel};
    gemm_osel_k<<<768, 256, 0, stream>>>(oa);
  }
  // ---- 9: combine + bias
  oadd_k<<<4096, 256, 0, stream>>>(out, P1o, P2o, bo);
}

// Round 14
// 237.357 us; speedup vs baseline: 1.1852x; 1.1852x over previous
//
#include <hip/hip_runtime.h>
#include <math.h>

// Problem constants (fixed by setup_inputs)
#define NB 2
#define NL 2048
#define NH 16
#define ND 64
#define NDM 1024
#define NU 409                  // max(1, 2048 // 5)
#define NUP 416                 // NU padded to multiple of 32; 416 = 26*16 = 13*32
#define NBH (NB*NH)             // 32
#define NROWS (NB*NL)           // 4096
#define NRTOT (NB*NH*NL)        // 65536
#define MTOT (NBH*NUP)          // 13312

typedef short bf16x8 __attribute__((ext_vector_type(8)));
typedef short bf16x4 __attribute__((ext_vector_type(4)));
typedef float f32x4  __attribute__((ext_vector_type(4)));

__device__ __forceinline__ short f2bf(float x) {   // RNE f32 -> bf16
  unsigned u = __float_as_uint(x);
  return (short)((u + 0x7FFFu + ((u >> 16) & 1u)) >> 16);
}
__device__ __forceinline__ float bf2f(short s) {
  return __uint_as_float(((unsigned)(unsigned short)s) << 16);
}

__device__ __forceinline__ void gload16(const short* g, short* l) {
  __builtin_amdgcn_global_load_lds(
      (const __attribute__((address_space(1))) void*)g,
      (__attribute__((address_space(3))) void*)l, 16, 0, 0);
}

// ---------------------------------------------------------------- multi-tensor f32 -> bf16 splits
struct SplitDesc { const float* in; short* a; short* b; short* c; int nc; int nblk; };
struct SplitArgs { SplitDesc d[7]; };

__global__ __launch_bounds__(256) void msplit_k(SplitArgs args) {
  const SplitDesc d = args.d[blockIdx.z];
  if ((int)blockIdx.x >= d.nblk) return;
  const size_t i = (size_t)blockIdx.x * 256 + threadIdx.x;
  const float4 x0 = ((const float4*)d.in)[2*i];
  const float4 x1 = ((const float4*)d.in)[2*i + 1];
  float x[8] = {x0.x,x0.y,x0.z,x0.w, x1.x,x1.y,x1.z,x1.w};
  bf16x8 va, vb;
  #pragma unroll
  for (int j = 0; j < 8; ++j) {
    const short A = f2bf(x[j]);
    va[j] = A;
    vb[j] = f2bf(x[j] - bf2f(A));
  }
  *(bf16x8*)(d.a + 8*i) = va;
  if (d.nc >= 2) *(bf16x8*)(d.b + 8*i) = vb;
}

// ---------------------------------------------------------------- mega projection GEMM (Q/K/V), full 128x128 tiles
// BK=64, 4 waves 2x2, wave 64x64 = 4x4 16x16 frags.
// chunk pairs (c=step>>4): c0 (a,a), c1 (a,b), c2 (b,a)
// LDS: linear dest for global_load_lds; SOURCE k-slot pre-swizzled s^=(row&7);
// fragment reads apply the same XOR (rule 21).
// 768 blocks; fid&7 = XCD, jd%3 = desc -> each CU hosts {Q,K,V}, equal work.
// mode 0: SC-scatter f32 + bias (Q)
// mode 1: fused K epilogue: bias + row-norm -> Kbf bf16 + f64 kbar partials
// mode 2: fused V epilogue: +bias, LDS transpose, coalesced bf16 Vt (bh,d,l)
struct GemmDesc {
  const short* X[2];
  const short* W[2];
  const float* bias;
  float* C;             // mode 0
  short* KbfVt;         // mode 1: Kbf; mode 2: Vt
  double* kpart;        // mode 1: [bh][32][64] f64
  int sbeg, send;       // step range; one step = 64 k-elems; chunk = step>>4
  int mode;
};
struct GemmArgs { GemmDesc d[3]; };

__global__ __launch_bounds__(256, 3) void gemm_mega_k(GemmArgs args) {
  __shared__ short As[128*64];   // 16 KB
  __shared__ short Bs[128*64];   // 16 KB
  const int fid = blockIdx.x;
  const int xcd = fid & 7, jd = fid >> 3;   // jd 0..95
  const int s = jd % 3, jj = jd / 3;        // desc s; tile jj 0..31
  const int tile = (xcd << 5) + jj;         // 0..255
  const int bx = tile & 7, by = tile >> 3;
  const GemmDesc d = args.d[s];
  const int tid = threadIdx.x;
  const int wv = tid >> 6, L = tid & 63;
  const int lr = L & 15, lg = L >> 4;
  const int n0 = bx << 7, m0 = by << 7;
  const int wm = (wv >> 1) << 6, wn = (wv & 1) << 6;
  const int sr = tid >> 3, ssl = tid & 7;

  f32x4 acc[4][4];
  #pragma unroll
  for (int i = 0; i < 4; ++i)
    #pragma unroll
    for (int j = 0; j < 4; ++j) acc[i][j] = (f32x4){0.f,0.f,0.f,0.f};

  for (int step = d.sbeg; step < d.send; ++step) {
    const int c = step >> 4, kk = (step & 15) << 6;
    const short *Xg, *Wg;
    switch (c) {
      case 0:  Xg = d.X[0]; Wg = d.W[0]; break;
      case 1:  Xg = d.X[0]; Wg = d.W[1]; break;
      default: Xg = d.X[1]; Wg = d.W[0]; break;
    }
    #pragma unroll
    for (int j = 0; j < 4; ++j) {
      const int row = (j << 5) + sr;
      const int slot = (ssl ^ (row & 7)) << 3;   // pre-swizzled k-slot
      gload16(Xg + (size_t)(m0 + row) * NDM + kk + slot, As + (j << 11) + (tid << 3));
      gload16(Wg + (size_t)(n0 + row) * NDM + kk + slot, Bs + (j << 11) + (tid << 3));
    }
    __syncthreads();
    #pragma unroll
    for (int c2 = 0; c2 < 2; ++c2) {
      const int sl = (((c2 << 2) + lg) ^ (lr & 7)) << 3;
      bf16x8 af[4], bfr[4];
      #pragma unroll
      for (int t = 0; t < 4; ++t) {
        af[t]  = *(const bf16x8*)(As + ((wm + (t << 4) + lr) << 6) + sl);
        bfr[t] = *(const bf16x8*)(Bs + ((wn + (t << 4) + lr) << 6) + sl);
      }
      #pragma unroll
      for (int mt = 0; mt < 4; ++mt)
        #pragma unroll
        for (int nt = 0; nt < 4; ++nt)
          acc[mt][nt] = __builtin_amdgcn_mfma_f32_16x16x32_bf16(bfr[nt], af[mt], acc[mt][nt], 0, 0, 0);
    }
    __syncthreads();
  }

  if (d.mode == 1) {
    // ---- fused K epilogue (full tile, verified round 8): k = acc + bias;
    //      |k| via shfl over lg groups; Kbf bf16 store; f64 kbar partials.
    const int b2 = by >> 4;
    const int hw = (bx << 1) + (wv & 1);          // head of this wave
    const int bh = (b2 << 4) + hw;
    const int seg = ((by & 15) << 1) + (wv >> 1); // 64-row segment within bh
    float kv[4][4][4];
    double inv[4];
    #pragma unroll
    for (int mt = 0; mt < 4; ++mt) {
      float ss = 0.f;
      #pragma unroll
      for (int nt = 0; nt < 4; ++nt) {
        const int n = n0 + wn + (nt << 4) + (lg << 2);
        const float4 b4 = *(const float4*)(d.bias + n);
        kv[mt][nt][0] = acc[mt][nt][0] + b4.x;
        kv[mt][nt][1] = acc[mt][nt][1] + b4.y;
        kv[mt][nt][2] = acc[mt][nt][2] + b4.z;
        kv[mt][nt][3] = acc[mt][nt][3] + b4.w;
        #pragma unroll
        for (int j = 0; j < 4; ++j) ss += kv[mt][nt][j] * kv[mt][nt][j];
      }
      ss += __shfl_xor(ss, 16);
      ss += __shfl_xor(ss, 32);
      inv[mt] = 1.0 / sqrt((double)ss);
    }
    #pragma unroll
    for (int mt = 0; mt < 4; ++mt) {
      const int l = (m0 + wm + (mt << 4) + lr) & (NL - 1);
      short* kp = d.KbfVt + (((size_t)bh * NL + l) << 6);
      #pragma unroll
      for (int nt = 0; nt < 4; ++nt) {
        const int dd = (nt << 4) + (lg << 2);
        bf16x4 o;
        #pragma unroll
        for (int j = 0; j < 4; ++j) o[j] = f2bf(kv[mt][nt][j]);
        *(bf16x4*)(kp + dd) = o;
      }
    }
    #pragma unroll
    for (int nt = 0; nt < 4; ++nt) {
      double p[4];
      #pragma unroll
      for (int j = 0; j < 4; ++j) {
        p[j] = 0.0;
        #pragma unroll
        for (int mt = 0; mt < 4; ++mt) p[j] += (double)kv[mt][nt][j] * inv[mt];
        p[j] += __shfl_xor(p[j], 1);
        p[j] += __shfl_xor(p[j], 2);
        p[j] += __shfl_xor(p[j], 4);
        p[j] += __shfl_xor(p[j], 8);
      }
      if (lr == 0) {
        const int dd = (nt << 4) + (lg << 2);
        double* kp = d.kpart + ((((size_t)bh << 5) + seg) << 6) + dd;
        kp[0] = p[0]; kp[1] = p[1]; kp[2] = p[2]; kp[3] = p[3];
      }
    }
  } else if (d.mode == 2) {
    // ---- fused V epilogue: +bias -> bf16 into LDS T(n,m) (XOR col swizzle),
    //      then coalesced 128B-contiguous stores into Vt[bh][d][l].
    #pragma unroll
    for (int nt = 0; nt < 4; ++nt) {
      const int nl = wn + (nt << 4) + (lg << 2);
      const float4 b4 = *(const float4*)(d.bias + n0 + nl);
      #pragma unroll
      for (int j2 = 0; j2 < 4; ++j2) {
        const int row = nl + j2;
        short* Tp = (row & 64) ? Bs : As;
        const int rr = row & 63;
        const float bj = (j2 == 0) ? b4.x : (j2 == 1) ? b4.y : (j2 == 2) ? b4.z : b4.w;
        const int sw = (row & 7) << 3;
        #pragma unroll
        for (int mt = 0; mt < 4; ++mt) {
          const int m = wm + (mt << 4) + lr;
          Tp[rr * 128 + (m ^ sw)] = f2bf(acc[mt][nt][j2] + bj);
        }
      }
    }
    __syncthreads();
    {
      const int r = tid >> 1, seg2 = tid & 1;
      const short* Tp = (r & 64) ? Bs : As;
      const int rr = r & 63, sw = (r & 7) << 3;
      const int ngl = n0 + r, h = ngl >> 6, dd2 = ngl & 63;
      const int bb = m0 >> 11, ll = m0 & (NL - 1);
      short* dst = d.KbfVt + (((size_t)((((bb << 4) + h) << 6) + dd2)) << 11) + ll + (seg2 << 6);
      #pragma unroll
      for (int i = 0; i < 8; ++i)
        *(bf16x8*)(dst + (i << 3)) =
            *(const bf16x8*)(Tp + rr * 128 + (((seg2 << 6) + (i << 3)) ^ sw));
    }
  } else {
    #pragma unroll
    for (int nt = 0; nt < 4; ++nt) {
      const int n = n0 + wn + (nt << 4) + (lg << 2);
      const float4 b4 = *(const float4*)(d.bias + n);
      #pragma unroll
      for (int mt = 0; mt < 4; ++mt) {
        f32x4 a = acc[mt][nt];
        a[0] += b4.x; a[1] += b4.y; a[2] += b4.z; a[3] += b4.w;
        const int m = m0 + wm + (mt << 4) + lr;
        const int bb = m >> 11, ll = m & (NL - 1);
        const int hh = n >> 6, dd = n & 63;
        *(f32x4*)(d.C + (((size_t)(bb*NH + hh)*NL + ll) << 6) + dd) = a;
      }
    }
  }
}

// ---------------------------------------------------------------- wtilde (+inline kbar reduce): wt[bh][j] f32, s0[bh] f64
__global__ __launch_bounds__(256) void wtilde_k(const float* __restrict__ Wq,
                                                const float* __restrict__ bq,
                                                const double* __restrict__ kpart,
                                                float* __restrict__ wt,
                                                double* __restrict__ s0) {
  __shared__ double kb[64];
  const int bh = blockIdx.x, h = bh & 15;
  const int tid = threadIdx.x;
  if (tid < 64) {
    double s = 0.0;
    #pragma unroll
    for (int seg = 0; seg < 32; ++seg)
      s += kpart[((((size_t)bh << 5) + seg) << 6) + tid];
    kb[tid] = s * (1.0 / NL);
  }
  __syncthreads();
  const int j = (blockIdx.y << 8) + tid;
  double a = 0.0;
  #pragma unroll 8
  for (int d = 0; d < 64; ++d)
    a += (double)Wq[(((size_t)((h << 6) + d)) << 10) + j] * kb[d];
  wt[((size_t)bh << 10) + j] = (float)a;
  if (blockIdx.y == 0 && tid < 64) {
    double p = (double)bq[(h << 6) + tid] * kb[tid];
    #pragma unroll
    for (int off = 32; off > 0; off >>= 1) p += __shfl_xor(p, off);
    if (tid == 0) s0[bh] = p;
  }
}

// ---------------------------------------------------------------- fused dotq+msq: ms[bh][l] = (x.wt + s0)/|q|
__global__ __launch_bounds__(256) void dotqms_k(const float* __restrict__ x,
                                                const float* __restrict__ Qb,
                                                const float* __restrict__ wt,
                                                const double* __restrict__ s0,
                                                float* __restrict__ ms) {
  __shared__ float xs[1024];
  __shared__ double sm[16][16];
  __shared__ double sq[16][16];
  const int r = blockIdx.x, b = r >> 11, l = r & (NL - 1);
  const int tid = threadIdx.x;
  ((float4*)xs)[tid] = ((const float4*)(x + ((size_t)r << 10)))[tid];
  __syncthreads();
  const int h = tid >> 4, t = tid & 15;
  const float* w = wt + ((size_t)((b << 4) + h) << 10);
  double a = 0.0;
  #pragma unroll 8
  for (int i = 0; i < 64; ++i) {
    const int j = t + (i << 4);
    a += (double)xs[j] * (double)w[j];
  }
  sm[h][t] = a;
  const float4 qv = *(const float4*)(Qb + (((size_t)((b << 4) + h) * NL + l) << 6) + (t << 2));
  sq[h][t] = (double)qv.x*qv.x + (double)qv.y*qv.y + (double)qv.z*qv.z + (double)qv.w*qv.w;
  __syncthreads();
  if (tid < 16) {
    double s = 0.0, ssq = 0.0;
    #pragma unroll
    for (int t2 = 0; t2 < 16; ++t2) { s += sm[tid][t2]; ssq += sq[tid][t2]; }
    ms[(((size_t)(b << 4) + tid) << 11) + l] = (float)((s + s0[(b << 4) + tid]) / sqrt(ssq));
  }
}

// ---------------------------------------------------------------- rank-based top-NU selection (+ inverse map; pad -> NU)
__global__ __launch_bounds__(256) void select_rank_k(const float* __restrict__ ms,
                                                     int* __restrict__ sel,
                                                     int* __restrict__ invsel) {
  __shared__ unsigned long long keys[NL];
  const int bh = blockIdx.x >> 3, seg = blockIdx.x & 7;
  const int tid = threadIdx.x;
  for (int l = tid; l < NL; l += 256) {
    unsigned u = __float_as_uint(ms[(size_t)bh * NL + l]);
    u = (u & 0x80000000u) ? ~u : (u | 0x80000000u);   // order-preserving map
    keys[l] = ((unsigned long long)u << 32) | (unsigned)(NL - 1 - l);
  }
  __syncthreads();
  const int r = (seg << 8) + tid;
  const unsigned long long mine = keys[r];
  int cnt = 0;
  #pragma unroll 8
  for (int l = 0; l < NL; ++l) cnt += (keys[l] > mine) ? 1 : 0;
  if (cnt < NU) sel[bh*NU + cnt] = r;
  invsel[(size_t)bh * NL + r] = (cnt < NU) ? cnt : NU;  // NU = zeroed pad row
}

// ---------------------------------------------------------------- fused attention with inline Q gather; split bf16 Csel out
__global__ __launch_bounds__(512) void fattn_k(const float* __restrict__ Qb,
                                               const int* __restrict__ sel,
                                               const short* __restrict__ Kbf,
                                               const short* __restrict__ Vt,
                                               short* __restrict__ Ca,
                                               short* __restrict__ Cb) {
  __shared__ short S[32*2048];        // 128 KB, row stride 4096 B
  __shared__ float inv_s[32];
  int bid = blockIdx.x;
  bid = (bid & 7) * 52 + (bid >> 3);  // 416 = 8*52 XCD chunks
  const int m0 = bid << 5;
  const int bh = m0 / NUP;
  const int u0 = m0 - bh * NUP;
  const int tid = threadIdx.x;
  const int w = tid >> 6, L = tid & 63;
  const int lr = L & 15, lg = L >> 4;

  // ---- Q fragments gathered from f32 Qb via sel (pad rows read row 0, discarded)
  bf16x8 qf[2][2];
  #pragma unroll
  for (int mt = 0; mt < 2; ++mt) {
    const int u = u0 + mt*16 + lr;
    const int lq = (u < NU) ? sel[bh*NU + u] : 0;
    const float* qp = Qb + (((size_t)bh*NL + lq) << 6) + lg*8;
    const float4 q0 = *(const float4*)qp;
    const float4 q1 = *(const float4*)(qp + 4);
    const float4 q2 = *(const float4*)(qp + 32);
    const float4 q3 = *(const float4*)(qp + 36);
    qf[mt][0][0]=f2bf(q0.x); qf[mt][0][1]=f2bf(q0.y); qf[mt][0][2]=f2bf(q0.z); qf[mt][0][3]=f2bf(q0.w);
    qf[mt][0][4]=f2bf(q1.x); qf[mt][0][5]=f2bf(q1.y); qf[mt][0][6]=f2bf(q1.z); qf[mt][0][7]=f2bf(q1.w);
    qf[mt][1][0]=f2bf(q2.x); qf[mt][1][1]=f2bf(q2.y); qf[mt][1][2]=f2bf(q2.z); qf[mt][1][3]=f2bf(q2.w);
    qf[mt][1][4]=f2bf(q3.x); qf[mt][1][5]=f2bf(q3.y); qf[mt][1][6]=f2bf(q3.z); qf[mt][1][7]=f2bf(q3.w);
  }
  const int nb = w << 8;
  const short* kb0 = Kbf + (((size_t)bh*NL + nb + lr) << 6) + lg*8;
  #pragma unroll 2
  for (int nt = 0; nt < 16; ++nt) {
    const short* kp = kb0 + ((size_t)nt << 10);
    const bf16x8 kf0 = *(const bf16x8*)kp;
    const bf16x8 kf1 = *(const bf16x8*)(kp + 32);
    #pragma unroll
    for (int mt = 0; mt < 2; ++mt) {
      f32x4 a = {0.f,0.f,0.f,0.f};
      a = __builtin_amdgcn_mfma_f32_16x16x32_bf16(kf0, qf[mt][0], a, 0, 0, 0);
      a = __builtin_amdgcn_mfma_f32_16x16x32_bf16(kf1, qf[mt][1], a, 0, 0, 0);
      const int m = mt*16 + lr;
      bf16x4 o;
      #pragma unroll
      for (int r = 0; r < 4; ++r) o[r] = f2bf(a[r] * 0.125f);
      const int byteoff = (m << 12) + ((((nb + nt*16 + lg*4) << 1)) ^ ((m & 7) << 4));
      *(bf16x4*)((char*)S + byteoff) = o;
    }
  }
  __syncthreads();

  #pragma unroll
  for (int j = 0; j < 4; ++j) {
    const int R = (w << 2) + j;
    char* rowp = (char*)S + (R << 12);
    const int sw = (R & 7) << 4;
    bf16x8 v[4];
    #pragma unroll
    for (int i = 0; i < 4; ++i)
      v[i] = *(const bf16x8*)(rowp + (((L << 6) + (i << 4)) ^ sw));
    float f[32];
    #pragma unroll
    for (int i = 0; i < 4; ++i)
      #pragma unroll
      for (int e = 0; e < 8; ++e) f[i*8+e] = bf2f(v[i][e]);
    float mx = f[0];
    #pragma unroll
    for (int i = 1; i < 32; ++i) mx = fmaxf(mx, f[i]);
    #pragma unroll
    for (int off = 32; off > 0; off >>= 1) mx = fmaxf(mx, __shfl_xor(mx, off));
    float sum = 0.f;
    #pragma unroll
    for (int i = 0; i < 32; ++i) { f[i] = __expf(f[i] - mx); sum += f[i]; }
    #pragma unroll
    for (int off = 32; off > 0; off >>= 1) sum += __shfl_xor(sum, off);
    bf16x8 p[4];
    #pragma unroll
    for (int i = 0; i < 4; ++i)
      #pragma unroll
      for (int e = 0; e < 8; ++e) p[i][e] = f2bf(f[i*8+e]);
    #pragma unroll
    for (int i = 0; i < 4; ++i)
      *(bf16x8*)(rowp + (((L << 6) + (i << 4)) ^ sw)) = p[i];
    if (L == 0) inv_s[R] = 1.f / sum;
  }
  __syncthreads();

  {
    const int mt = w & 1, dt = w >> 1;
    const int m = mt*16 + lr;
    const char* arow = (const char*)S + (m << 12);
    const int sw = (m & 7) << 4;
    const short* vrow = Vt + (((size_t)bh*ND + dt*16 + lr) << 11) + lg*8;
    f32x4 acc0 = {0.f,0.f,0.f,0.f}, acc1 = {0.f,0.f,0.f,0.f};
    for (int k0 = 0; k0 < NL; k0 += 64) {
      const bf16x8 p0 = *(const bf16x8*)(arow + ((((k0 + lg*8) << 1)) ^ sw));
      const bf16x8 p1 = *(const bf16x8*)(arow + ((((k0 + 32 + lg*8) << 1)) ^ sw));
      const bf16x8 v0 = *(const bf16x8*)(vrow + k0);
      const bf16x8 v1 = *(const bf16x8*)(vrow + k0 + 32);
      acc0 = __builtin_amdgcn_mfma_f32_16x16x32_bf16(p0, v0, acc0, 0, 0, 0);
      acc1 = __builtin_amdgcn_mfma_f32_16x16x32_bf16(p1, v1, acc1, 0, 0, 0);
    }
    const int ub = u0 + mt*16 + (lg << 2);
    #pragma unroll
    for (int r = 0; r < 4; ++r) {
      float val = (acc0[r] + acc1[r]) * inv_s[mt*16 + (lg << 2) + r];
      if (ub + r >= NU) val = 0.f;                 // zero pad rows (incl. row NU)
      const size_t off = (((size_t)m0 + mt*16 + (lg << 2) + r) << 6) + dt*16 + lr;
      const short A = f2bf(val);
      Ca[off] = A;
      Cb[off] = f2bf(val - bf2f(A));
    }
  }
}

// ---------------------------------------------------------------- O projection GEMM (X gathered from Csel via invsel)
// 768 blocks; split-K 3-way interleaved per CU (3 blocks/CU). Full 128x128 tile.
struct OselArgs {
  const short* Xa; const short* Xb;
  const short* Wa; const short* Wb;
  float* C0; float* C1; float* C2;   // thirds: steps [0,16) [16,32) [32,48)
  const int* invsel;
};

__global__ __launch_bounds__(256, 3) void gemm_osel_k(OselArgs ar) {
  __shared__ short As[128*64];   // 16 KB
  __shared__ short Bs[128*64];   // 16 KB
  __shared__ int utbl[2048];     // 8 KB
  const int fid = blockIdx.x;
  const int xcd = fid & 7, jd = fid >> 3;   // jd 0..95
  const int zi = jd % 3;
  const int o = (xcd << 5) + (jd / 3);      // 0..255
  const int bx = o & 7, by = o >> 3;
  const int sbeg = zi << 4, send = sbeg + 16;
  float* C = (zi == 0) ? ar.C0 : (zi == 1) ? ar.C1 : ar.C2;
  const int tid = threadIdx.x;
  const int wv = tid >> 6, L = tid & 63;
  const int lr = L & 15, lg = L >> 4;
  const int n0 = bx << 7, m0 = by << 7;
  const int wm = (wv >> 1) << 6, wn = (wv & 1) << 6;
  const int sr = tid >> 3, ssl = tid & 7;
  const int b2 = by >> 4;

  #pragma unroll
  for (int e = 0; e < 8; ++e) {
    const int idx = (tid << 3) + e;             // 0..2047
    const int row = idx >> 4, h = idx & 15;
    utbl[idx] = ar.invsel[((((size_t)b2 << 4) + h) << 11) + ((m0 + row) & (NL - 1))];
  }
  __syncthreads();

  f32x4 acc[4][4];
  #pragma unroll
  for (int i = 0; i < 4; ++i)
    #pragma unroll
    for (int j = 0; j < 4; ++j) acc[i][j] = (f32x4){0.f,0.f,0.f,0.f};

  for (int step = sbeg; step < send; ++step) {
    const int c = step >> 4, kk = (step & 15) << 6;
    const short* Wg = (c == 1) ? ar.Wb : ar.Wa;   // c0:(a,a) c1:(a,b) c2:(b,a)
    const short* Xs = (c == 2) ? ar.Xb : ar.Xa;
    #pragma unroll
    for (int j = 0; j < 4; ++j) {
      const int row = (j << 5) + sr;
      const int slot = (ssl ^ (row & 7)) << 3;
      const int h = step & 15;                  // one head per 64-wide step
      const int u = utbl[(row << 4) + h];
      gload16(Xs + (((size_t)((b2 << 4) + h) * NUP + u) << 6) + slot,
              As + (j << 11) + (tid << 3));
      gload16(Wg + (size_t)(n0 + row) * NDM + kk + slot, Bs + (j << 11) + (tid << 3));
    }
    __syncthreads();
    #pragma unroll
    for (int c2 = 0; c2 < 2; ++c2) {
      const int sl = (((c2 << 2) + lg) ^ (lr & 7)) << 3;
      bf16x8 af[4], bfr[4];
      #pragma unroll
      for (int t = 0; t < 4; ++t) {
        af[t]  = *(const bf16x8*)(As + ((wm + (t << 4) + lr) << 6) + sl);
        bfr[t] = *(const bf16x8*)(Bs + ((wn + (t << 4) + lr) << 6) + sl);
      }
      #pragma unroll
      for (int mt = 0; mt < 4; ++mt)
        #pragma unroll
        for (int nt = 0; nt < 4; ++nt)
          acc[mt][nt] = __builtin_amdgcn_mfma_f32_16x16x32_bf16(bfr[nt], af[mt], acc[mt][nt], 0, 0, 0);
    }
    __syncthreads();
  }

  #pragma unroll
  for (int nt = 0; nt < 4; ++nt) {
    const int n = n0 + wn + (nt << 4) + (lg << 2);
    #pragma unroll
    for (int mt = 0; mt < 4; ++mt) {
      const int m = m0 + wm + (mt << 4) + lr;
      *(f32x4*)(C + ((size_t)m << 10) + n) = acc[mt][nt];
    }
  }
}

// ---------------------------------------------------------------- out += P1 + P2 + bias
__global__ __launch_bounds__(256) void oadd_k(float* __restrict__ out,
                                              const float* __restrict__ P1,
                                              const float* __restrict__ P2,
                                              const float* __restrict__ bo) {
  const size_t i4 = (size_t)blockIdx.x * 256 + threadIdx.x;
  const size_t i = i4 << 2;
  float4 a = *(float4*)(out + i);
  const float4 b = *(const float4*)(P1 + i);
  const float4 c = *(const float4*)(P2 + i);
  const float4 d = *(const float4*)(bo + ((i4 & 255) << 2));
  a.x += b.x + c.x + d.x; a.y += b.y + c.y + d.y;
  a.z += b.z + c.z + d.z; a.w += b.w + c.w + d.w;
  *(float4*)(out + i) = a;
}

// ---------------------------------------------------------------- launch
extern "C" void kernel_launch(void* const* d_in, const int* in_sizes, int n_in,
                              void* d_out, int out_size, void* d_ws, size_t ws_size,
                              hipStream_t stream)
{
  (void)in_sizes; (void)n_in; (void)out_size; (void)ws_size;
  const float* queries = (const float*)d_in[0];
  const float* keys    = (const float*)d_in[1];
  const float* values  = (const float*)d_in[2];
  const float* Wq = (const float*)d_in[3];  const float* bq = (const float*)d_in[4];
  const float* Wk = (const float*)d_in[5];  const float* bk = (const float*)d_in[6];
  const float* Wv = (const float*)d_in[7];  const float* bv = (const float*)d_in[8];
  const float* Wo = (const float*)d_in[9];  const float* bo = (const float*)d_in[10];
  float* out = (float*)d_out;

  char* base = (char*)d_ws;
  #define MB(x) ((size_t)(x) << 20)

  short* Qa   = (short*)(base + MB(0));    // queries split a (dead after mega)
  short* Qb2  = (short*)(base + MB(8));    // queries split b (dead after mega)
  short* Ka   = (short*)(base + MB(16));   // -> P2 (osel partial) after mega
  short* Kb2  = (short*)(base + MB(24));
  short* Kbf  = (short*)(base + MB(32));   // written by mega K epilogue
  short* Vbf  = (short*)(base + MB(40));   // -> CselA/CselB after mega
  float* Qb   = (float*)(base + MB(48));   // Q proj f32 -> P1o after fattn
  short* Vt   = (short*)(base + MB(64));   // written during mega (mode-2 epilogue)
  short* Wqa  = (short*)(base + MB(72));
  short* Wqb  = (short*)(base + MB(74));
  short* Wka  = (short*)(base + MB(76));
  short* Wkb  = (short*)(base + MB(78));
  short* Wvbf = (short*)(base + MB(80));
  short* Woa  = (short*)(base + MB(82));
  short* Wob  = (short*)(base + MB(84));
  char* sm = base + MB(86);
  double* kpart  = (double*)sm;  sm += 524288;    // [32][32][64] f64
  float*  wt     = (float*)sm;   sm += 131072;    // [32][1024] f32
  double* s0     = (double*)sm;  sm += 512;
  float*  msb    = (float*)sm;   sm += 262144;
  int*    sel    = (int*)sm;     sm += 65536;
  int*    invsel = (int*)sm;     sm += 262144;

  // time-multiplexed aliases
  short* CselA = Vbf;                       // 1.625 MiB
  short* CselB = (short*)(base + MB(42));   // 1.625 MiB
  float* P1o   = Qb;                        // after fattn
  float* P2o   = (float*)Ka;                // 16 MiB (Ka+Kb2 region, dead after mega)

  // ---- 1: all splits in one launch (inputs + weights)
  {
    SplitArgs a;
    a.d[0] = {queries, Qa, Qb2, nullptr, 2, 2048};
    a.d[1] = {keys,    Ka, Kb2, nullptr, 2, 2048};
    a.d[2] = {values,  Vbf, nullptr, nullptr, 1, 2048};
    a.d[3] = {Wq, Wqa, Wqb, nullptr, 2, 512};
    a.d[4] = {Wk, Wka, Wkb, nullptr, 2, 512};
    a.d[5] = {Wv, Wvbf, nullptr, nullptr, 1, 512};
    a.d[6] = {Wo, Woa, Wob, nullptr, 2, 512};
    msplit_k<<<dim3(2048,1,7), 256, 0, stream>>>(a);
  }
  // ---- 2: balanced mega GEMM, full tiles: Q(48) + K(48, fused norm/kbar
  //         epilogue) + V(16, fused transpose epilogue); 768 blocks, 3/CU
  {
    GemmArgs g;
    g.d[0] = {{Qa,Qb2},   {Wqa,Wqb},   bq, Qb,      nullptr, nullptr, 0, 48, 0};
    g.d[1] = {{Ka,Kb2},   {Wka,Wkb},   bk, nullptr, Kbf,     kpart,   0, 48, 1};
    g.d[2] = {{Vbf,Vbf},  {Wvbf,Wvbf}, bv, nullptr, Vt,      nullptr, 0, 16, 2};
    gemm_mega_k<<<768, 256, 0, stream>>>(g);
  }
  // ---- 3-5: ranking chain
  wtilde_k<<<dim3(NBH,4), 256, 0, stream>>>(Wq, bq, kpart, wt, s0);
  dotqms_k<<<NROWS, 256, 0, stream>>>(queries, Qb, wt, s0, msb);
  select_rank_k<<<NBH*8, 256, 0, stream>>>(msb, sel, invsel);

  // ---- 6: fused attention (inline Q gather; split bf16 Csel; pad rows zeroed)
  fattn_k<<<MTOT/32, 512, 0, stream>>>(Qb, sel, Kbf, Vt, CselA, CselB);

  // ---- 7: output projection (X gathered from Csel via invsel), split-K 3-way
  {
    OselArgs oa = {CselA, CselB, Woa, Wob, out, P1o, P2o, invsel};
    gemm_osel_k<<<768, 256, 0, stream>>>(oa);
  }
  // ---- 8: combine + bias
  oadd_k<<<4096, 256, 0, stream>>>(out, P1o, P2o, bo);
}

// Round 15
// 233.886 us; speedup vs baseline: 1.2028x; 1.0148x over previous
//
#include <hip/hip_runtime.h>
#include <math.h>

// Problem constants (fixed by setup_inputs)
#define NB 2
#define NL 2048
#define NH 16
#define ND 64
#define NDM 1024
#define NU 409                  // max(1, 2048 // 5)
#define NUP 416                 // NU padded to multiple of 32; 416 = 26*16 = 13*32
#define NBH (NB*NH)             // 32
#define NROWS (NB*NL)           // 4096
#define NRTOT (NB*NH*NL)        // 65536
#define MTOT (NBH*NUP)          // 13312

typedef short bf16x8 __attribute__((ext_vector_type(8)));
typedef short bf16x4 __attribute__((ext_vector_type(4)));
typedef float f32x4  __attribute__((ext_vector_type(4)));

__device__ __forceinline__ short f2bf(float x) {   // RNE f32 -> bf16
  unsigned u = __float_as_uint(x);
  return (short)((u + 0x7FFFu + ((u >> 16) & 1u)) >> 16);
}
__device__ __forceinline__ float bf2f(short s) {
  return __uint_as_float(((unsigned)(unsigned short)s) << 16);
}

__device__ __forceinline__ void gload16(const short* g, short* l) {
  __builtin_amdgcn_global_load_lds(
      (const __attribute__((address_space(1))) void*)g,
      (__attribute__((address_space(3))) void*)l, 16, 0, 0);
}

// ---------------------------------------------------------------- multi-tensor f32 -> bf16 splits
struct SplitDesc { const float* in; short* a; short* b; short* c; int nc; int nblk; };
struct SplitArgs { SplitDesc d[7]; };

__global__ __launch_bounds__(256) void msplit_k(SplitArgs args) {
  const SplitDesc d = args.d[blockIdx.z];
  if ((int)blockIdx.x >= d.nblk) return;
  const size_t i = (size_t)blockIdx.x * 256 + threadIdx.x;
  const float4 x0 = ((const float4*)d.in)[2*i];
  const float4 x1 = ((const float4*)d.in)[2*i + 1];
  float x[8] = {x0.x,x0.y,x0.z,x0.w, x1.x,x1.y,x1.z,x1.w};
  bf16x8 va, vb;
  #pragma unroll
  for (int j = 0; j < 8; ++j) {
    const short A = f2bf(x[j]);
    va[j] = A;
    vb[j] = f2bf(x[j] - bf2f(A));
  }
  *(bf16x8*)(d.a + 8*i) = va;
  if (d.nc >= 2) *(bf16x8*)(d.b + 8*i) = vb;
}

// ---------------------------------------------------------------- mega projection GEMM (Q/K/V), full 128x128 tiles
// BK=64, 4 waves 2x2, wave 64x64 = 4x4 16x16 frags.
// chunk pairs (c=step>>4): c0 (a,a), c1 (a,b), c2 (b,a)
// LDS: linear dest for global_load_lds; SOURCE k-slot pre-swizzled s^=(row&7);
// fragment reads apply the same XOR (rule 21).
// 768 blocks; fid&7 = XCD, jd%3 = desc -> each CU hosts {Q,K,V}, equal work.
// mode 1: fused K epilogue: bias + row-norm -> Kbf bf16 + f64 kbar partials
// mode 2: fused V epilogue: +bias, LDS transpose, coalesced bf16 Vt (bh,d,l)
// mode 3: fused Q epilogue: bias -> Qbf bf16 (bh,l,d) + row |q|^2 f32 (sqv)
struct GemmDesc {
  const short* X[2];
  const short* W[2];
  const float* bias;
  short* KbfVt;         // mode 1: Kbf; mode 2: Vt; mode 3: Qbf
  double* kpart;        // mode 1: [bh][32][64] f64
  float* sq;            // mode 3: [bh][2048] f32
  int sbeg, send;       // step range; one step = 64 k-elems; chunk = step>>4
  int mode;
};
struct GemmArgs { GemmDesc d[3]; };

__global__ __launch_bounds__(256, 3) void gemm_mega_k(GemmArgs args) {
  __shared__ short As[128*64];   // 16 KB
  __shared__ short Bs[128*64];   // 16 KB
  const int fid = blockIdx.x;
  const int xcd = fid & 7, jd = fid >> 3;   // jd 0..95
  const int s = jd % 3, jj = jd / 3;        // desc s; tile jj 0..31
  const int tile = (xcd << 5) + jj;         // 0..255
  const int bx = tile & 7, by = tile >> 3;
  const GemmDesc d = args.d[s];
  const int tid = threadIdx.x;
  const int wv = tid >> 6, L = tid & 63;
  const int lr = L & 15, lg = L >> 4;
  const int n0 = bx << 7, m0 = by << 7;
  const int wm = (wv >> 1) << 6, wn = (wv & 1) << 6;
  const int sr = tid >> 3, ssl = tid & 7;

  f32x4 acc[4][4];
  #pragma unroll
  for (int i = 0; i < 4; ++i)
    #pragma unroll
    for (int j = 0; j < 4; ++j) acc[i][j] = (f32x4){0.f,0.f,0.f,0.f};

  for (int step = d.sbeg; step < d.send; ++step) {
    const int c = step >> 4, kk = (step & 15) << 6;
    const short *Xg, *Wg;
    switch (c) {
      case 0:  Xg = d.X[0]; Wg = d.W[0]; break;
      case 1:  Xg = d.X[0]; Wg = d.W[1]; break;
      default: Xg = d.X[1]; Wg = d.W[0]; break;
    }
    #pragma unroll
    for (int j = 0; j < 4; ++j) {
      const int row = (j << 5) + sr;
      const int slot = (ssl ^ (row & 7)) << 3;   // pre-swizzled k-slot
      gload16(Xg + (size_t)(m0 + row) * NDM + kk + slot, As + (j << 11) + (tid << 3));
      gload16(Wg + (size_t)(n0 + row) * NDM + kk + slot, Bs + (j << 11) + (tid << 3));
    }
    __syncthreads();
    #pragma unroll
    for (int c2 = 0; c2 < 2; ++c2) {
      const int sl = (((c2 << 2) + lg) ^ (lr & 7)) << 3;
      bf16x8 af[4], bfr[4];
      #pragma unroll
      for (int t = 0; t < 4; ++t) {
        af[t]  = *(const bf16x8*)(As + ((wm + (t << 4) + lr) << 6) + sl);
        bfr[t] = *(const bf16x8*)(Bs + ((wn + (t << 4) + lr) << 6) + sl);
      }
      #pragma unroll
      for (int mt = 0; mt < 4; ++mt)
        #pragma unroll
        for (int nt = 0; nt < 4; ++nt)
          acc[mt][nt] = __builtin_amdgcn_mfma_f32_16x16x32_bf16(bfr[nt], af[mt], acc[mt][nt], 0, 0, 0);
    }
    __syncthreads();
  }

  if (d.mode == 1) {
    // ---- fused K epilogue: k = acc + bias; |k| via shfl over lg groups;
    //      Kbf bf16 store; f64 kbar partials.
    const int b2 = by >> 4;
    const int hw = (bx << 1) + (wv & 1);          // head of this wave
    const int bh = (b2 << 4) + hw;
    const int seg = ((by & 15) << 1) + (wv >> 1); // 64-row segment within bh
    float kv[4][4][4];
    double inv[4];
    #pragma unroll
    for (int mt = 0; mt < 4; ++mt) {
      float ss = 0.f;
      #pragma unroll
      for (int nt = 0; nt < 4; ++nt) {
        const int n = n0 + wn + (nt << 4) + (lg << 2);
        const float4 b4 = *(const float4*)(d.bias + n);
        kv[mt][nt][0] = acc[mt][nt][0] + b4.x;
        kv[mt][nt][1] = acc[mt][nt][1] + b4.y;
        kv[mt][nt][2] = acc[mt][nt][2] + b4.z;
        kv[mt][nt][3] = acc[mt][nt][3] + b4.w;
        #pragma unroll
        for (int j = 0; j < 4; ++j) ss += kv[mt][nt][j] * kv[mt][nt][j];
      }
      ss += __shfl_xor(ss, 16);
      ss += __shfl_xor(ss, 32);
      inv[mt] = 1.0 / sqrt((double)ss);
    }
    #pragma unroll
    for (int mt = 0; mt < 4; ++mt) {
      const int l = (m0 + wm + (mt << 4) + lr) & (NL - 1);
      short* kp = d.KbfVt + (((size_t)bh * NL + l) << 6);
      #pragma unroll
      for (int nt = 0; nt < 4; ++nt) {
        const int dd = (nt << 4) + (lg << 2);
        bf16x4 o;
        #pragma unroll
        for (int j = 0; j < 4; ++j) o[j] = f2bf(kv[mt][nt][j]);
        *(bf16x4*)(kp + dd) = o;
      }
    }
    #pragma unroll
    for (int nt = 0; nt < 4; ++nt) {
      double p[4];
      #pragma unroll
      for (int j = 0; j < 4; ++j) {
        p[j] = 0.0;
        #pragma unroll
        for (int mt = 0; mt < 4; ++mt) p[j] += (double)kv[mt][nt][j] * inv[mt];
        p[j] += __shfl_xor(p[j], 1);
        p[j] += __shfl_xor(p[j], 2);
        p[j] += __shfl_xor(p[j], 4);
        p[j] += __shfl_xor(p[j], 8);
      }
      if (lr == 0) {
        const int dd = (nt << 4) + (lg << 2);
        double* kp = d.kpart + ((((size_t)bh << 5) + seg) << 6) + dd;
        kp[0] = p[0]; kp[1] = p[1]; kp[2] = p[2]; kp[3] = p[3];
      }
    }
  } else if (d.mode == 3) {
    // ---- fused Q epilogue: q = acc + bias; |q|^2 via shfl; Qbf bf16 + sqv f32
    const int b2 = by >> 4;
    const int hw = (bx << 1) + (wv & 1);
    const int bh = (b2 << 4) + hw;
    #pragma unroll
    for (int mt = 0; mt < 4; ++mt) {
      float kv[4][4];
      float ss = 0.f;
      #pragma unroll
      for (int nt = 0; nt < 4; ++nt) {
        const int n = n0 + wn + (nt << 4) + (lg << 2);
        const float4 b4 = *(const float4*)(d.bias + n);
        kv[nt][0] = acc[mt][nt][0] + b4.x;
        kv[nt][1] = acc[mt][nt][1] + b4.y;
        kv[nt][2] = acc[mt][nt][2] + b4.z;
        kv[nt][3] = acc[mt][nt][3] + b4.w;
        #pragma unroll
        for (int j = 0; j < 4; ++j) ss += kv[nt][j] * kv[nt][j];
      }
      ss += __shfl_xor(ss, 16);
      ss += __shfl_xor(ss, 32);
      const int l = (m0 + wm + (mt << 4) + lr) & (NL - 1);
      if (lg == 0) d.sq[((size_t)bh << 11) + l] = ss;
      short* qp = d.KbfVt + (((size_t)bh * NL + l) << 6);
      #pragma unroll
      for (int nt = 0; nt < 4; ++nt) {
        const int dd = (nt << 4) + (lg << 2);
        bf16x4 o;
        #pragma unroll
        for (int j = 0; j < 4; ++j) o[j] = f2bf(kv[nt][j]);
        *(bf16x4*)(qp + dd) = o;
      }
    }
  } else {
    // ---- fused V epilogue: +bias -> bf16 into LDS T(n,m) (XOR col swizzle),
    //      then coalesced 128B-contiguous stores into Vt[bh][d][l].
    #pragma unroll
    for (int nt = 0; nt < 4; ++nt) {
      const int nl = wn + (nt << 4) + (lg << 2);
      const float4 b4 = *(const float4*)(d.bias + n0 + nl);
      #pragma unroll
      for (int j2 = 0; j2 < 4; ++j2) {
        const int row = nl + j2;
        short* Tp = (row & 64) ? Bs : As;
        const int rr = row & 63;
        const float bj = (j2 == 0) ? b4.x : (j2 == 1) ? b4.y : (j2 == 2) ? b4.z : b4.w;
        const int sw = (row & 7) << 3;
        #pragma unroll
        for (int mt = 0; mt < 4; ++mt) {
          const int m = wm + (mt << 4) + lr;
          Tp[rr * 128 + (m ^ sw)] = f2bf(acc[mt][nt][j2] + bj);
        }
      }
    }
    __syncthreads();
    {
      const int r = tid >> 1, seg2 = tid & 1;
      const short* Tp = (r & 64) ? Bs : As;
      const int rr = r & 63, sw = (r & 7) << 3;
      const int ngl = n0 + r, h = ngl >> 6, dd2 = ngl & 63;
      const int bb = m0 >> 11, ll = m0 & (NL - 1);
      short* dst = d.KbfVt + (((size_t)((((bb << 4) + h) << 6) + dd2)) << 11) + ll + (seg2 << 6);
      #pragma unroll
      for (int i = 0; i < 8; ++i)
        *(bf16x8*)(dst + (i << 3)) =
            *(const bf16x8*)(Tp + rr * 128 + (((seg2 << 6) + (i << 3)) ^ sw));
    }
  }
}

// ---------------------------------------------------------------- wtilde (+inline kbar reduce): wt[bh][j] f32, s0[bh] f64
__global__ __launch_bounds__(256) void wtilde_k(const float* __restrict__ Wq,
                                                const float* __restrict__ bq,
                                                const double* __restrict__ kpart,
                                                float* __restrict__ wt,
                                                double* __restrict__ s0) {
  __shared__ double kb[64];
  const int bh = blockIdx.x, h = bh & 15;
  const int tid = threadIdx.x;
  if (tid < 64) {
    double s = 0.0;
    #pragma unroll
    for (int seg = 0; seg < 32; ++seg)
      s += kpart[((((size_t)bh << 5) + seg) << 6) + tid];
    kb[tid] = s * (1.0 / NL);
  }
  __syncthreads();
  const int j = (blockIdx.y << 8) + tid;
  double a = 0.0;
  #pragma unroll 8
  for (int d = 0; d < 64; ++d)
    a += (double)Wq[(((size_t)((h << 6) + d)) << 10) + j] * kb[d];
  wt[((size_t)bh << 10) + j] = (float)a;
  if (blockIdx.y == 0 && tid < 64) {
    double p = (double)bq[(h << 6) + tid] * kb[tid];
    #pragma unroll
    for (int off = 32; off > 0; off >>= 1) p += __shfl_xor(p, off);
    if (tid == 0) s0[bh] = p;
  }
}

// ---------------------------------------------------------------- fused dotq+msq: ms[bh][l] = (x.wt + s0)/sqrt(sqv)
__global__ __launch_bounds__(256) void dotqms_k(const float* __restrict__ x,
                                                const float* __restrict__ sqv,
                                                const float* __restrict__ wt,
                                                const double* __restrict__ s0,
                                                float* __restrict__ ms) {
  __shared__ float xs[1024];
  __shared__ double sm[16][16];
  const int r = blockIdx.x, b = r >> 11, l = r & (NL - 1);
  const int tid = threadIdx.x;
  ((float4*)xs)[tid] = ((const float4*)(x + ((size_t)r << 10)))[tid];
  __syncthreads();
  const int h = tid >> 4, t = tid & 15;
  const float* w = wt + ((size_t)((b << 4) + h) << 10);
  double a = 0.0;
  #pragma unroll 8
  for (int i = 0; i < 64; ++i) {
    const int j = t + (i << 4);
    a += (double)xs[j] * (double)w[j];
  }
  sm[h][t] = a;
  __syncthreads();
  if (tid < 16) {
    double s = 0.0;
    #pragma unroll
    for (int t2 = 0; t2 < 16; ++t2) s += sm[tid][t2];
    const size_t ro = (((size_t)(b << 4) + tid) << 11) + l;
    ms[ro] = (float)((s + s0[(b << 4) + tid]) / sqrt((double)sqv[ro]));
  }
}

// ---------------------------------------------------------------- rank-based top-NU selection (+ inverse map; pad -> NU)
__global__ __launch_bounds__(256) void select_rank_k(const float* __restrict__ ms,
                                                     int* __restrict__ sel,
                                                     int* __restrict__ invsel) {
  __shared__ unsigned long long keys[NL];
  const int bh = blockIdx.x >> 3, seg = blockIdx.x & 7;
  const int tid = threadIdx.x;
  for (int l = tid; l < NL; l += 256) {
    unsigned u = __float_as_uint(ms[(size_t)bh * NL + l]);
    u = (u & 0x80000000u) ? ~u : (u | 0x80000000u);   // order-preserving map
    keys[l] = ((unsigned long long)u << 32) | (unsigned)(NL - 1 - l);
  }
  __syncthreads();
  const int r = (seg << 8) + tid;
  const unsigned long long mine = keys[r];
  int cnt = 0;
  #pragma unroll 8
  for (int l = 0; l < NL; ++l) cnt += (keys[l] > mine) ? 1 : 0;
  if (cnt < NU) sel[bh*NU + cnt] = r;
  invsel[(size_t)bh * NL + r] = (cnt < NU) ? cnt : NU;  // NU = zeroed pad row
}

// ---------------------------------------------------------------- fused attention; bf16 Q gather; single bf16 Csel out
__global__ __launch_bounds__(512) void fattn_k(const short* __restrict__ Qbf,
                                               const int* __restrict__ sel,
                                               const short* __restrict__ Kbf,
                                               const short* __restrict__ Vt,
                                               short* __restrict__ Csel) {
  __shared__ short S[32*2048];        // 128 KB, row stride 4096 B
  __shared__ float inv_s[32];
  int bid = blockIdx.x;
  bid = (bid & 7) * 52 + (bid >> 3);  // 416 = 8*52 XCD chunks
  const int m0 = bid << 5;
  const int bh = m0 / NUP;
  const int u0 = m0 - bh * NUP;
  const int tid = threadIdx.x;
  const int w = tid >> 6, L = tid & 63;
  const int lr = L & 15, lg = L >> 4;

  // ---- Q fragments gathered from bf16 Qbf via sel (pad rows read row 0, discarded)
  bf16x8 qf[2][2];
  #pragma unroll
  for (int mt = 0; mt < 2; ++mt) {
    const int u = u0 + mt*16 + lr;
    const int lq = (u < NU) ? sel[bh*NU + u] : 0;
    const short* qp = Qbf + (((size_t)bh*NL + lq) << 6) + lg*8;
    qf[mt][0] = *(const bf16x8*)qp;
    qf[mt][1] = *(const bf16x8*)(qp + 32);
  }
  const int nb = w << 8;
  const short* kb0 = Kbf + (((size_t)bh*NL + nb + lr) << 6) + lg*8;
  #pragma unroll 2
  for (int nt = 0; nt < 16; ++nt) {
    const short* kp = kb0 + ((size_t)nt << 10);
    const bf16x8 kf0 = *(const bf16x8*)kp;
    const bf16x8 kf1 = *(const bf16x8*)(kp + 32);
    #pragma unroll
    for (int mt = 0; mt < 2; ++mt) {
      f32x4 a = {0.f,0.f,0.f,0.f};
      a = __builtin_amdgcn_mfma_f32_16x16x32_bf16(kf0, qf[mt][0], a, 0, 0, 0);
      a = __builtin_amdgcn_mfma_f32_16x16x32_bf16(kf1, qf[mt][1], a, 0, 0, 0);
      const int m = mt*16 + lr;
      bf16x4 o;
      #pragma unroll
      for (int r = 0; r < 4; ++r) o[r] = f2bf(a[r] * 0.125f);
      const int byteoff = (m << 12) + ((((nb + nt*16 + lg*4) << 1)) ^ ((m & 7) << 4));
      *(bf16x4*)((char*)S + byteoff) = o;
    }
  }
  __syncthreads();

  #pragma unroll
  for (int j = 0; j < 4; ++j) {
    const int R = (w << 2) + j;
    char* rowp = (char*)S + (R << 12);
    const int sw = (R & 7) << 4;
    bf16x8 v[4];
    #pragma unroll
    for (int i = 0; i < 4; ++i)
      v[i] = *(const bf16x8*)(rowp + (((L << 6) + (i << 4)) ^ sw));
    float f[32];
    #pragma unroll
    for (int i = 0; i < 4; ++i)
      #pragma unroll
      for (int e = 0; e < 8; ++e) f[i*8+e] = bf2f(v[i][e]);
    float mx = f[0];
    #pragma unroll
    for (int i = 1; i < 32; ++i) mx = fmaxf(mx, f[i]);
    #pragma unroll
    for (int off = 32; off > 0; off >>= 1) mx = fmaxf(mx, __shfl_xor(mx, off));
    float sum = 0.f;
    #pragma unroll
    for (int i = 0; i < 32; ++i) { f[i] = __expf(f[i] - mx); sum += f[i]; }
    #pragma unroll
    for (int off = 32; off > 0; off >>= 1) sum += __shfl_xor(sum, off);
    bf16x8 p[4];
    #pragma unroll
    for (int i = 0; i < 4; ++i)
      #pragma unroll
      for (int e = 0; e < 8; ++e) p[i][e] = f2bf(f[i*8+e]);
    #pragma unroll
    for (int i = 0; i < 4; ++i)
      *(bf16x8*)(rowp + (((L << 6) + (i << 4)) ^ sw)) = p[i];
    if (L == 0) inv_s[R] = 1.f / sum;
  }
  __syncthreads();

  {
    const int mt = w & 1, dt = w >> 1;
    const int m = mt*16 + lr;
    const char* arow = (const char*)S + (m << 12);
    const int sw = (m & 7) << 4;
    const short* vrow = Vt + (((size_t)bh*ND + dt*16 + lr) << 11) + lg*8;
    f32x4 acc0 = {0.f,0.f,0.f,0.f}, acc1 = {0.f,0.f,0.f,0.f};
    for (int k0 = 0; k0 < NL; k0 += 64) {
      const bf16x8 p0 = *(const bf16x8*)(arow + ((((k0 + lg*8) << 1)) ^ sw));
      const bf16x8 p1 = *(const bf16x8*)(arow + ((((k0 + 32 + lg*8) << 1)) ^ sw));
      const bf16x8 v0 = *(const bf16x8*)(vrow + k0);
      const bf16x8 v1 = *(const bf16x8*)(vrow + k0 + 32);
      acc0 = __builtin_amdgcn_mfma_f32_16x16x32_bf16(p0, v0, acc0, 0, 0, 0);
      acc1 = __builtin_amdgcn_mfma_f32_16x16x32_bf16(p1, v1, acc1, 0, 0, 0);
    }
    const int ub = u0 + mt*16 + (lg << 2);
    #pragma unroll
    for (int r = 0; r < 4; ++r) {
      float val = (acc0[r] + acc1[r]) * inv_s[mt*16 + (lg << 2) + r];
      if (ub + r >= NU) val = 0.f;                 // zero pad rows (incl. row NU)
      const size_t off = (((size_t)m0 + mt*16 + (lg << 2) + r) << 6) + dt*16 + lr;
      Csel[off] = f2bf(val);
    }
  }
}

// ---------------------------------------------------------------- O projection GEMM (X gathered from Csel via invsel)
// 2 chunks (Csel x {Woa,Wob}); 1024 blocks, split-K 4-way interleaved per CU.
struct OselArgs {
  const short* X;
  const short* Wa; const short* Wb;
  float* C0; float* C1; float* C2; float* C3;   // quarters: 8 steps each
  const int* invsel;
};

__global__ __launch_bounds__(256, 3) void gemm_osel_k(OselArgs ar) {
  __shared__ short As[128*64];   // 16 KB
  __shared__ short Bs[128*64];   // 16 KB
  __shared__ int utbl[2048];     // 8 KB
  const int fid = blockIdx.x;
  const int xcd = fid & 7, jd = fid >> 3;   // jd 0..127
  const int zi = jd & 3;
  const int o = (xcd << 5) + (jd >> 2);     // 0..255
  const int bx = o & 7, by = o >> 3;
  const int sbeg = zi << 3, send = sbeg + 8;
  float* C = (zi == 0) ? ar.C0 : (zi == 1) ? ar.C1 : (zi == 2) ? ar.C2 : ar.C3;
  const int tid = threadIdx.x;
  const int wv = tid >> 6, L = tid & 63;
  const int lr = L & 15, lg = L >> 4;
  const int n0 = bx << 7, m0 = by << 7;
  const int wm = (wv >> 1) << 6, wn = (wv & 1) << 6;
  const int sr = tid >> 3, ssl = tid & 7;
  const int b2 = by >> 4;

  #pragma unroll
  for (int e = 0; e < 8; ++e) {
    const int idx = (tid << 3) + e;             // 0..2047
    const int row = idx >> 4, h = idx & 15;
    utbl[idx] = ar.invsel[((((size_t)b2 << 4) + h) << 11) + ((m0 + row) & (NL - 1))];
  }
  __syncthreads();

  f32x4 acc[4][4];
  #pragma unroll
  for (int i = 0; i < 4; ++i)
    #pragma unroll
    for (int j = 0; j < 4; ++j) acc[i][j] = (f32x4){0.f,0.f,0.f,0.f};

  for (int step = sbeg; step < send; ++step) {
    const int c = step >> 4, kk = (step & 15) << 6;
    const short* Wg = c ? ar.Wb : ar.Wa;        // c0:(Csel,Woa) c1:(Csel,Wob)
    #pragma unroll
    for (int j = 0; j < 4; ++j) {
      const int row = (j << 5) + sr;
      const int slot = (ssl ^ (row & 7)) << 3;
      const int h = step & 15;                  // one head per 64-wide step
      const int u = utbl[(row << 4) + h];
      gload16(ar.X + (((size_t)((b2 << 4) + h) * NUP + u) << 6) + slot,
              As + (j << 11) + (tid << 3));
      gload16(Wg + (size_t)(n0 + row) * NDM + kk + slot, Bs + (j << 11) + (tid << 3));
    }
    __syncthreads();
    #pragma unroll
    for (int c2 = 0; c2 < 2; ++c2) {
      const int sl = (((c2 << 2) + lg) ^ (lr & 7)) << 3;
      bf16x8 af[4], bfr[4];
      #pragma unroll
      for (int t = 0; t < 4; ++t) {
        af[t]  = *(const bf16x8*)(As + ((wm + (t << 4) + lr) << 6) + sl);
        bfr[t] = *(const bf16x8*)(Bs + ((wn + (t << 4) + lr) << 6) + sl);
      }
      #pragma unroll
      for (int mt = 0; mt < 4; ++mt)
        #pragma unroll
        for (int nt = 0; nt < 4; ++nt)
          acc[mt][nt] = __builtin_amdgcn_mfma_f32_16x16x32_bf16(bfr[nt], af[mt], acc[mt][nt], 0, 0, 0);
    }
    __syncthreads();
  }

  #pragma unroll
  for (int nt = 0; nt < 4; ++nt) {
    const int n = n0 + wn + (nt << 4) + (lg << 2);
    #pragma unroll
    for (int mt = 0; mt < 4; ++mt) {
      const int m = m0 + wm + (mt << 4) + lr;
      *(f32x4*)(C + ((size_t)m << 10) + n) = acc[mt][nt];
    }
  }
}

// ---------------------------------------------------------------- out += P1 + P2 + P3 + bias
__global__ __launch_bounds__(256) void oadd_k(float* __restrict__ out,
                                              const float* __restrict__ P1,
                                              const float* __restrict__ P2,
                                              const float* __restrict__ P3,
                                              const float* __restrict__ bo) {
  const size_t i4 = (size_t)blockIdx.x * 256 + threadIdx.x;
  const size_t i = i4 << 2;
  float4 a = *(float4*)(out + i);
  const float4 b = *(const float4*)(P1 + i);
  const float4 c = *(const float4*)(P2 + i);
  const float4 e = *(const float4*)(P3 + i);
  const float4 d = *(const float4*)(bo + ((i4 & 255) << 2));
  a.x += b.x + c.x + e.x + d.x; a.y += b.y + c.y + e.y + d.y;
  a.z += b.z + c.z + e.z + d.z; a.w += b.w + c.w + e.w + d.w;
  *(float4*)(out + i) = a;
}

// ---------------------------------------------------------------- launch
extern "C" void kernel_launch(void* const* d_in, const int* in_sizes, int n_in,
                              void* d_out, int out_size, void* d_ws, size_t ws_size,
                              hipStream_t stream)
{
  (void)in_sizes; (void)n_in; (void)out_size; (void)ws_size;
  const float* queries = (const float*)d_in[0];
  const float* keys    = (const float*)d_in[1];
  const float* values  = (const float*)d_in[2];
  const float* Wq = (const float*)d_in[3];  const float* bq = (const float*)d_in[4];
  const float* Wk = (const float*)d_in[5];  const float* bk = (const float*)d_in[6];
  const float* Wv = (const float*)d_in[7];  const float* bv = (const float*)d_in[8];
  const float* Wo = (const float*)d_in[9];  const float* bo = (const float*)d_in[10];
  float* out = (float*)d_out;

  char* base = (char*)d_ws;
  #define MB(x) ((size_t)(x) << 20)

  short* Qa   = (short*)(base + MB(0));    // queries split a -> P3o after mega
  short* Qb2  = (short*)(base + MB(8));    // queries split b
  short* Ka   = (short*)(base + MB(16));   // keys split a -> P2o after mega
  short* Kb2  = (short*)(base + MB(24));
  short* Kbf  = (short*)(base + MB(32));   // written by mega K epilogue
  short* Vbf  = (short*)(base + MB(40));   // -> Csel after mega
  short* Qbf  = (short*)(base + MB(48));   // written by mega Q epilogue
  float* P1o  = (float*)(base + MB(56));   // osel partial 1 (16 MiB)
  short* Vt   = (short*)(base + MB(72));   // written by mega V epilogue
  short* Wqa  = (short*)(base + MB(80));
  short* Wqb  = (short*)(base + MB(82));
  short* Wka  = (short*)(base + MB(84));
  short* Wkb  = (short*)(base + MB(86));
  short* Wvbf = (short*)(base + MB(88));
  short* Woa  = (short*)(base + MB(90));
  short* Wob  = (short*)(base + MB(92));
  char* sm = base + MB(94);
  double* kpart  = (double*)sm;  sm += 524288;    // [32][32][64] f64
  float*  wt     = (float*)sm;   sm += 131072;    // [32][1024] f32
  double* s0     = (double*)sm;  sm += 512;
  float*  sqv    = (float*)sm;   sm += 262144;    // [32][2048] f32
  float*  msb    = (float*)sm;   sm += 262144;
  int*    sel    = (int*)sm;     sm += 65536;
  int*    invsel = (int*)sm;     sm += 262144;

  // time-multiplexed aliases
  short* Csel = Vbf;                        // 1.625 MiB, after mega
  float* P2o  = (float*)Ka;                 // 16 MiB (Ka+Kb2), dead after mega
  float* P3o  = (float*)Qa;                 // 16 MiB (Qa+Qb2), dead after mega

  // ---- 1: all splits in one launch (inputs + weights)
  {
    SplitArgs a;
    a.d[0] = {queries, Qa, Qb2, nullptr, 2, 2048};
    a.d[1] = {keys,    Ka, Kb2, nullptr, 2, 2048};
    a.d[2] = {values,  Vbf, nullptr, nullptr, 1, 2048};
    a.d[3] = {Wq, Wqa, Wqb, nullptr, 2, 512};
    a.d[4] = {Wk, Wka, Wkb, nullptr, 2, 512};
    a.d[5] = {Wv, Wvbf, nullptr, nullptr, 1, 512};
    a.d[6] = {Wo, Woa, Wob, nullptr, 2, 512};
    msplit_k<<<dim3(2048,1,7), 256, 0, stream>>>(a);
  }
  // ---- 2: balanced mega GEMM, full tiles: Q(48, fused bf16+|q|^2 epilogue)
  //         + K(48, fused norm/kbar) + V(16, fused transpose); 768 blocks
  {
    GemmArgs g;
    g.d[0] = {{Qa,Qb2},  {Wqa,Wqb},   bq, Qbf, nullptr, sqv,     0, 48, 3};
    g.d[1] = {{Ka,Kb2},  {Wka,Wkb},   bk, Kbf, kpart,   nullptr, 0, 48, 1};
    g.d[2] = {{Vbf,Vbf}, {Wvbf,Wvbf}, bv, Vt,  nullptr, nullptr, 0, 16, 2};
    gemm_mega_k<<<768, 256, 0, stream>>>(g);
  }
  // ---- 3-5: ranking chain
  wtilde_k<<<dim3(NBH,4), 256, 0, stream>>>(Wq, bq, kpart, wt, s0);
  dotqms_k<<<NROWS, 256, 0, stream>>>(queries, sqv, wt, s0, msb);
  select_rank_k<<<NBH*8, 256, 0, stream>>>(msb, sel, invsel);

  // ---- 6: fused attention (bf16 Q gather; single bf16 Csel; pad rows zeroed)
  fattn_k<<<MTOT/32, 512, 0, stream>>>(Qbf, sel, Kbf, Vt, Csel);

  // ---- 7: output projection (X gathered from Csel via invsel), split-K 4-way
  {
    OselArgs oa = {Csel, Woa, Wob, out, P1o, P2o, P3o, invsel};
    gemm_osel_k<<<1024, 256, 0, stream>>>(oa);
  }
  // ---- 8: combine + bias
  oadd_k<<<4096, 256, 0, stream>>>(out, P1o, P2o, P3o, bo);
}

// Round 16
// 224.488 us; speedup vs baseline: 1.2532x; 1.0419x over previous
//
#include <hip/hip_runtime.h>
#include <math.h>

// Problem constants (fixed by setup_inputs)
#define NB 2
#define NL 2048
#define NH 16
#define ND 64
#define NDM 1024
#define NU 409                  // max(1, 2048 // 5)
#define NUP 416                 // NU padded to multiple of 32; 416 = 26*16 = 13*32
#define NBH (NB*NH)             // 32
#define NROWS (NB*NL)           // 4096
#define NRTOT (NB*NH*NL)        // 65536
#define MTOT (NBH*NUP)          // 13312

typedef short bf16x8 __attribute__((ext_vector_type(8)));
typedef short bf16x4 __attribute__((ext_vector_type(4)));
typedef float f32x4  __attribute__((ext_vector_type(4)));

__device__ __forceinline__ short f2bf(float x) {   // RNE f32 -> bf16
  unsigned u = __float_as_uint(x);
  return (short)((u + 0x7FFFu + ((u >> 16) & 1u)) >> 16);
}
__device__ __forceinline__ float bf2f(short s) {
  return __uint_as_float(((unsigned)(unsigned short)s) << 16);
}

__device__ __forceinline__ void gload16(const short* g, short* l) {
  __builtin_amdgcn_global_load_lds(
      (const __attribute__((address_space(1))) void*)g,
      (__attribute__((address_space(3))) void*)l, 16, 0, 0);
}

// ---------------------------------------------------------------- multi-tensor f32 -> bf16 splits
struct SplitDesc { const float* in; short* a; short* b; short* c; int nc; int nblk; };
struct SplitArgs { SplitDesc d[7]; };

__global__ __launch_bounds__(256) void msplit_k(SplitArgs args) {
  const SplitDesc d = args.d[blockIdx.z];
  if ((int)blockIdx.x >= d.nblk) return;
  const size_t i = (size_t)blockIdx.x * 256 + threadIdx.x;
  const float4 x0 = ((const float4*)d.in)[2*i];
  const float4 x1 = ((const float4*)d.in)[2*i + 1];
  float x[8] = {x0.x,x0.y,x0.z,x0.w, x1.x,x1.y,x1.z,x1.w};
  bf16x8 va, vb;
  #pragma unroll
  for (int j = 0; j < 8; ++j) {
    const short A = f2bf(x[j]);
    va[j] = A;
    vb[j] = f2bf(x[j] - bf2f(A));
  }
  *(bf16x8*)(d.a + 8*i) = va;
  if (d.nc >= 2) *(bf16x8*)(d.b + 8*i) = vb;
}

// ---------------------------------------------------------------- mega projection GEMM (Q/K/V), full 128x128 tiles
// BK=64, 4 waves 2x2, wave 64x64 = 4x4 16x16 frags.
// chunk pairs (c=step>>4): c0 (a,a), c1 (a,b), c2 (b,a)
// LDS: linear dest for global_load_lds; SOURCE k-slot pre-swizzled s^=(row&7);
// fragment reads apply the same XOR (rule 21).
// 768 blocks; fid&7 = XCD, jd%3 = desc -> each CU hosts {Q,K,V}, equal work.
// mode 1: fused K epilogue: bias + row-norm -> Kbf bf16 + f64 kbar partials
// mode 2: fused V epilogue: +bias, LDS transpose, coalesced bf16 Vt (bh,d,l)
// mode 3: fused Q epilogue: bias -> Qbf bf16 (bh,l,d) + row |q|^2 f32 (sqv)
struct GemmDesc {
  const short* X[2];
  const short* W[2];
  const float* bias;
  short* KbfVt;         // mode 1: Kbf; mode 2: Vt; mode 3: Qbf
  double* kpart;        // mode 1: [bh][32][64] f64
  float* sq;            // mode 3: [bh][2048] f32
  int sbeg, send;       // step range; one step = 64 k-elems; chunk = step>>4
  int mode;
};
struct GemmArgs { GemmDesc d[3]; };

__global__ __launch_bounds__(256, 3) void gemm_mega_k(GemmArgs args) {
  __shared__ short As[128*64];   // 16 KB
  __shared__ short Bs[128*64];   // 16 KB
  const int fid = blockIdx.x;
  const int xcd = fid & 7, jd = fid >> 3;   // jd 0..95
  const int s = jd % 3, jj = jd / 3;        // desc s; tile jj 0..31
  const int tile = (xcd << 5) + jj;         // 0..255
  const int bx = tile & 7, by = tile >> 3;
  const GemmDesc d = args.d[s];
  const int tid = threadIdx.x;
  const int wv = tid >> 6, L = tid & 63;
  const int lr = L & 15, lg = L >> 4;
  const int n0 = bx << 7, m0 = by << 7;
  const int wm = (wv >> 1) << 6, wn = (wv & 1) << 6;
  const int sr = tid >> 3, ssl = tid & 7;

  f32x4 acc[4][4];
  #pragma unroll
  for (int i = 0; i < 4; ++i)
    #pragma unroll
    for (int j = 0; j < 4; ++j) acc[i][j] = (f32x4){0.f,0.f,0.f,0.f};

  for (int step = d.sbeg; step < d.send; ++step) {
    const int c = step >> 4, kk = (step & 15) << 6;
    const short *Xg, *Wg;
    switch (c) {
      case 0:  Xg = d.X[0]; Wg = d.W[0]; break;
      case 1:  Xg = d.X[0]; Wg = d.W[1]; break;
      default: Xg = d.X[1]; Wg = d.W[0]; break;
    }
    #pragma unroll
    for (int j = 0; j < 4; ++j) {
      const int row = (j << 5) + sr;
      const int slot = (ssl ^ (row & 7)) << 3;   // pre-swizzled k-slot
      gload16(Xg + (size_t)(m0 + row) * NDM + kk + slot, As + (j << 11) + (tid << 3));
      gload16(Wg + (size_t)(n0 + row) * NDM + kk + slot, Bs + (j << 11) + (tid << 3));
    }
    __syncthreads();
    #pragma unroll
    for (int c2 = 0; c2 < 2; ++c2) {
      const int sl = (((c2 << 2) + lg) ^ (lr & 7)) << 3;
      bf16x8 af[4], bfr[4];
      #pragma unroll
      for (int t = 0; t < 4; ++t) {
        af[t]  = *(const bf16x8*)(As + ((wm + (t << 4) + lr) << 6) + sl);
        bfr[t] = *(const bf16x8*)(Bs + ((wn + (t << 4) + lr) << 6) + sl);
      }
      #pragma unroll
      for (int mt = 0; mt < 4; ++mt)
        #pragma unroll
        for (int nt = 0; nt < 4; ++nt)
          acc[mt][nt] = __builtin_amdgcn_mfma_f32_16x16x32_bf16(bfr[nt], af[mt], acc[mt][nt], 0, 0, 0);
    }
    __syncthreads();
  }

  if (d.mode == 1) {
    // ---- fused K epilogue: k = acc + bias; |k| via shfl over lg groups;
    //      Kbf bf16 store; f64 kbar partials.
    const int b2 = by >> 4;
    const int hw = (bx << 1) + (wv & 1);          // head of this wave
    const int bh = (b2 << 4) + hw;
    const int seg = ((by & 15) << 1) + (wv >> 1); // 64-row segment within bh
    float kv[4][4][4];
    double inv[4];
    #pragma unroll
    for (int mt = 0; mt < 4; ++mt) {
      float ss = 0.f;
      #pragma unroll
      for (int nt = 0; nt < 4; ++nt) {
        const int n = n0 + wn + (nt << 4) + (lg << 2);
        const float4 b4 = *(const float4*)(d.bias + n);
        kv[mt][nt][0] = acc[mt][nt][0] + b4.x;
        kv[mt][nt][1] = acc[mt][nt][1] + b4.y;
        kv[mt][nt][2] = acc[mt][nt][2] + b4.z;
        kv[mt][nt][3] = acc[mt][nt][3] + b4.w;
        #pragma unroll
        for (int j = 0; j < 4; ++j) ss += kv[mt][nt][j] * kv[mt][nt][j];
      }
      ss += __shfl_xor(ss, 16);
      ss += __shfl_xor(ss, 32);
      inv[mt] = 1.0 / sqrt((double)ss);
    }
    #pragma unroll
    for (int mt = 0; mt < 4; ++mt) {
      const int l = (m0 + wm + (mt << 4) + lr) & (NL - 1);
      short* kp = d.KbfVt + (((size_t)bh * NL + l) << 6);
      #pragma unroll
      for (int nt = 0; nt < 4; ++nt) {
        const int dd = (nt << 4) + (lg << 2);
        bf16x4 o;
        #pragma unroll
        for (int j = 0; j < 4; ++j) o[j] = f2bf(kv[mt][nt][j]);
        *(bf16x4*)(kp + dd) = o;
      }
    }
    #pragma unroll
    for (int nt = 0; nt < 4; ++nt) {
      double p[4];
      #pragma unroll
      for (int j = 0; j < 4; ++j) {
        p[j] = 0.0;
        #pragma unroll
        for (int mt = 0; mt < 4; ++mt) p[j] += (double)kv[mt][nt][j] * inv[mt];
        p[j] += __shfl_xor(p[j], 1);
        p[j] += __shfl_xor(p[j], 2);
        p[j] += __shfl_xor(p[j], 4);
        p[j] += __shfl_xor(p[j], 8);
      }
      if (lr == 0) {
        const int dd = (nt << 4) + (lg << 2);
        double* kp = d.kpart + ((((size_t)bh << 5) + seg) << 6) + dd;
        kp[0] = p[0]; kp[1] = p[1]; kp[2] = p[2]; kp[3] = p[3];
      }
    }
  } else if (d.mode == 3) {
    // ---- fused Q epilogue: q = acc + bias; |q|^2 via shfl; Qbf bf16 + sqv f32
    const int b2 = by >> 4;
    const int hw = (bx << 1) + (wv & 1);
    const int bh = (b2 << 4) + hw;
    #pragma unroll
    for (int mt = 0; mt < 4; ++mt) {
      float kv[4][4];
      float ss = 0.f;
      #pragma unroll
      for (int nt = 0; nt < 4; ++nt) {
        const int n = n0 + wn + (nt << 4) + (lg << 2);
        const float4 b4 = *(const float4*)(d.bias + n);
        kv[nt][0] = acc[mt][nt][0] + b4.x;
        kv[nt][1] = acc[mt][nt][1] + b4.y;
        kv[nt][2] = acc[mt][nt][2] + b4.z;
        kv[nt][3] = acc[mt][nt][3] + b4.w;
        #pragma unroll
        for (int j = 0; j < 4; ++j) ss += kv[nt][j] * kv[nt][j];
      }
      ss += __shfl_xor(ss, 16);
      ss += __shfl_xor(ss, 32);
      const int l = (m0 + wm + (mt << 4) + lr) & (NL - 1);
      if (lg == 0) d.sq[((size_t)bh << 11) + l] = ss;
      short* qp = d.KbfVt + (((size_t)bh * NL + l) << 6);
      #pragma unroll
      for (int nt = 0; nt < 4; ++nt) {
        const int dd = (nt << 4) + (lg << 2);
        bf16x4 o;
        #pragma unroll
        for (int j = 0; j < 4; ++j) o[j] = f2bf(kv[nt][j]);
        *(bf16x4*)(qp + dd) = o;
      }
    }
  } else {
    // ---- fused V epilogue: +bias -> bf16 into LDS T(n,m) (XOR col swizzle),
    //      then coalesced 128B-contiguous stores into Vt[bh][d][l].
    #pragma unroll
    for (int nt = 0; nt < 4; ++nt) {
      const int nl = wn + (nt << 4) + (lg << 2);
      const float4 b4 = *(const float4*)(d.bias + n0 + nl);
      #pragma unroll
      for (int j2 = 0; j2 < 4; ++j2) {
        const int row = nl + j2;
        short* Tp = (row & 64) ? Bs : As;
        const int rr = row & 63;
        const float bj = (j2 == 0) ? b4.x : (j2 == 1) ? b4.y : (j2 == 2) ? b4.z : b4.w;
        const int sw = (row & 7) << 3;
        #pragma unroll
        for (int mt = 0; mt < 4; ++mt) {
          const int m = wm + (mt << 4) + lr;
          Tp[rr * 128 + (m ^ sw)] = f2bf(acc[mt][nt][j2] + bj);
        }
      }
    }
    __syncthreads();
    {
      const int r = tid >> 1, seg2 = tid & 1;
      const short* Tp = (r & 64) ? Bs : As;
      const int rr = r & 63, sw = (r & 7) << 3;
      const int ngl = n0 + r, h = ngl >> 6, dd2 = ngl & 63;
      const int bb = m0 >> 11, ll = m0 & (NL - 1);
      short* dst = d.KbfVt + (((size_t)((((bb << 4) + h) << 6) + dd2)) << 11) + ll + (seg2 << 6);
      #pragma unroll
      for (int i = 0; i < 8; ++i)
        *(bf16x8*)(dst + (i << 3)) =
            *(const bf16x8*)(Tp + rr * 128 + (((seg2 << 6) + (i << 3)) ^ sw));
    }
  }
}

// ---------------------------------------------------------------- wtilde (+inline kbar reduce): wt[bh][j] f32, s0[bh] f64
__global__ __launch_bounds__(256) void wtilde_k(const float* __restrict__ Wq,
                                                const float* __restrict__ bq,
                                                const double* __restrict__ kpart,
                                                float* __restrict__ wt,
                                                double* __restrict__ s0) {
  __shared__ double kb[64];
  const int bh = blockIdx.x, h = bh & 15;
  const int tid = threadIdx.x;
  if (tid < 64) {
    double s = 0.0;
    #pragma unroll
    for (int seg = 0; seg < 32; ++seg)
      s += kpart[((((size_t)bh << 5) + seg) << 6) + tid];
    kb[tid] = s * (1.0 / NL);
  }
  __syncthreads();
  const int j = (blockIdx.y << 8) + tid;
  double a = 0.0;
  #pragma unroll 8
  for (int d = 0; d < 64; ++d)
    a += (double)Wq[(((size_t)((h << 6) + d)) << 10) + j] * kb[d];
  wt[((size_t)bh << 10) + j] = (float)a;
  if (blockIdx.y == 0 && tid < 64) {
    double p = (double)bq[(h << 6) + tid] * kb[tid];
    #pragma unroll
    for (int off = 32; off > 0; off >>= 1) p += __shfl_xor(p, off);
    if (tid == 0) s0[bh] = p;
  }
}

// ---------------------------------------------------------------- fused dotq+msq: ms[bh][l] = (x.wt + s0)/sqrt(sqv)
__global__ __launch_bounds__(256) void dotqms_k(const float* __restrict__ x,
                                                const float* __restrict__ sqv,
                                                const float* __restrict__ wt,
                                                const double* __restrict__ s0,
                                                float* __restrict__ ms) {
  __shared__ float xs[1024];
  __shared__ double sm[16][16];
  const int r = blockIdx.x, b = r >> 11, l = r & (NL - 1);
  const int tid = threadIdx.x;
  ((float4*)xs)[tid] = ((const float4*)(x + ((size_t)r << 10)))[tid];
  __syncthreads();
  const int h = tid >> 4, t = tid & 15;
  const float* w = wt + ((size_t)((b << 4) + h) << 10);
  double a = 0.0;
  #pragma unroll 8
  for (int i = 0; i < 64; ++i) {
    const int j = t + (i << 4);
    a += (double)xs[j] * (double)w[j];
  }
  sm[h][t] = a;
  __syncthreads();
  if (tid < 16) {
    double s = 0.0;
    #pragma unroll
    for (int t2 = 0; t2 < 16; ++t2) s += sm[tid][t2];
    const size_t ro = (((size_t)(b << 4) + tid) << 11) + l;
    ms[ro] = (float)((s + s0[(b << 4) + tid]) / sqrt((double)sqv[ro]));
  }
}

// ---------------------------------------------------------------- rank-based top-NU selection (+ inverse map; pad -> NU)
__global__ __launch_bounds__(256) void select_rank_k(const float* __restrict__ ms,
                                                     int* __restrict__ sel,
                                                     int* __restrict__ invsel) {
  __shared__ unsigned long long keys[NL];
  const int bh = blockIdx.x >> 3, seg = blockIdx.x & 7;
  const int tid = threadIdx.x;
  for (int l = tid; l < NL; l += 256) {
    unsigned u = __float_as_uint(ms[(size_t)bh * NL + l]);
    u = (u & 0x80000000u) ? ~u : (u | 0x80000000u);   // order-preserving map
    keys[l] = ((unsigned long long)u << 32) | (unsigned)(NL - 1 - l);
  }
  __syncthreads();
  const int r = (seg << 8) + tid;
  const unsigned long long mine = keys[r];
  int cnt = 0;
  #pragma unroll 8
  for (int l = 0; l < NL; ++l) cnt += (keys[l] > mine) ? 1 : 0;
  if (cnt < NU) sel[bh*NU + cnt] = r;
  invsel[(size_t)bh * NL + r] = (cnt < NU) ? cnt : NU;  // NU = zeroed pad row
}

// ---------------------------------------------------------------- fused attention; bf16 Q gather; single bf16 Csel out
__global__ __launch_bounds__(512) void fattn_k(const short* __restrict__ Qbf,
                                               const int* __restrict__ sel,
                                               const short* __restrict__ Kbf,
                                               const short* __restrict__ Vt,
                                               short* __restrict__ Csel) {
  __shared__ short S[32*2048];        // 128 KB, row stride 4096 B
  __shared__ float inv_s[32];
  int bid = blockIdx.x;
  bid = (bid & 7) * 52 + (bid >> 3);  // 416 = 8*52 XCD chunks
  const int m0 = bid << 5;
  const int bh = m0 / NUP;
  const int u0 = m0 - bh * NUP;
  const int tid = threadIdx.x;
  const int w = tid >> 6, L = tid & 63;
  const int lr = L & 15, lg = L >> 4;

  // ---- Q fragments gathered from bf16 Qbf via sel (pad rows read row 0, discarded)
  bf16x8 qf[2][2];
  #pragma unroll
  for (int mt = 0; mt < 2; ++mt) {
    const int u = u0 + mt*16 + lr;
    const int lq = (u < NU) ? sel[bh*NU + u] : 0;
    const short* qp = Qbf + (((size_t)bh*NL + lq) << 6) + lg*8;
    qf[mt][0] = *(const bf16x8*)qp;
    qf[mt][1] = *(const bf16x8*)(qp + 32);
  }
  const int nb = w << 8;
  const short* kb0 = Kbf + (((size_t)bh*NL + nb + lr) << 6) + lg*8;
  __builtin_amdgcn_s_setprio(1);      // T5: favor MFMA-issuing waves
  #pragma unroll 2
  for (int nt = 0; nt < 16; ++nt) {
    const short* kp = kb0 + ((size_t)nt << 10);
    const bf16x8 kf0 = *(const bf16x8*)kp;
    const bf16x8 kf1 = *(const bf16x8*)(kp + 32);
    #pragma unroll
    for (int mt = 0; mt < 2; ++mt) {
      f32x4 a = {0.f,0.f,0.f,0.f};
      a = __builtin_amdgcn_mfma_f32_16x16x32_bf16(kf0, qf[mt][0], a, 0, 0, 0);
      a = __builtin_amdgcn_mfma_f32_16x16x32_bf16(kf1, qf[mt][1], a, 0, 0, 0);
      const int m = mt*16 + lr;
      bf16x4 o;
      #pragma unroll
      for (int r = 0; r < 4; ++r) o[r] = f2bf(a[r] * 0.125f);
      const int byteoff = (m << 12) + ((((nb + nt*16 + lg*4) << 1)) ^ ((m & 7) << 4));
      *(bf16x4*)((char*)S + byteoff) = o;
    }
  }
  __builtin_amdgcn_s_setprio(0);
  __syncthreads();

  #pragma unroll
  for (int j = 0; j < 4; ++j) {
    const int R = (w << 2) + j;
    char* rowp = (char*)S + (R << 12);
    const int sw = (R & 7) << 4;
    bf16x8 v[4];
    #pragma unroll
    for (int i = 0; i < 4; ++i)
      v[i] = *(const bf16x8*)(rowp + (((L << 6) + (i << 4)) ^ sw));
    float f[32];
    #pragma unroll
    for (int i = 0; i < 4; ++i)
      #pragma unroll
      for (int e = 0; e < 8; ++e) f[i*8+e] = bf2f(v[i][e]);
    float mx = f[0];
    #pragma unroll
    for (int i = 1; i < 32; ++i) mx = fmaxf(mx, f[i]);
    #pragma unroll
    for (int off = 32; off > 0; off >>= 1) mx = fmaxf(mx, __shfl_xor(mx, off));
    float sum = 0.f;
    #pragma unroll
    for (int i = 0; i < 32; ++i) { f[i] = __expf(f[i] - mx); sum += f[i]; }
    #pragma unroll
    for (int off = 32; off > 0; off >>= 1) sum += __shfl_xor(sum, off);
    bf16x8 p[4];
    #pragma unroll
    for (int i = 0; i < 4; ++i)
      #pragma unroll
      for (int e = 0; e < 8; ++e) p[i][e] = f2bf(f[i*8+e]);
    #pragma unroll
    for (int i = 0; i < 4; ++i)
      *(bf16x8*)(rowp + (((L << 6) + (i << 4)) ^ sw)) = p[i];
    if (L == 0) inv_s[R] = 1.f / sum;
  }
  __syncthreads();

  {
    const int mt = w & 1, dt = w >> 1;
    const int m = mt*16 + lr;
    const char* arow = (const char*)S + (m << 12);
    const int sw = (m & 7) << 4;
    const short* vrow = Vt + (((size_t)bh*ND + dt*16 + lr) << 11) + lg*8;
    f32x4 acc0 = {0.f,0.f,0.f,0.f}, acc1 = {0.f,0.f,0.f,0.f};
    __builtin_amdgcn_s_setprio(1);    // T5
    for (int k0 = 0; k0 < NL; k0 += 64) {
      const bf16x8 p0 = *(const bf16x8*)(arow + ((((k0 + lg*8) << 1)) ^ sw));
      const bf16x8 p1 = *(const bf16x8*)(arow + ((((k0 + 32 + lg*8) << 1)) ^ sw));
      const bf16x8 v0 = *(const bf16x8*)(vrow + k0);
      const bf16x8 v1 = *(const bf16x8*)(vrow + k0 + 32);
      acc0 = __builtin_amdgcn_mfma_f32_16x16x32_bf16(p0, v0, acc0, 0, 0, 0);
      acc1 = __builtin_amdgcn_mfma_f32_16x16x32_bf16(p1, v1, acc1, 0, 0, 0);
    }
    __builtin_amdgcn_s_setprio(0);
    const int ub = u0 + mt*16 + (lg << 2);
    #pragma unroll
    for (int r = 0; r < 4; ++r) {
      float val = (acc0[r] + acc1[r]) * inv_s[mt*16 + (lg << 2) + r];
      if (ub + r >= NU) val = 0.f;                 // zero pad rows (incl. row NU)
      const size_t off = (((size_t)m0 + mt*16 + (lg << 2) + r) << 6) + dt*16 + lr;
      Csel[off] = f2bf(val);
    }
  }
}

// ---------------------------------------------------------------- O projection GEMM (X gathered from Csel via invsel)
// No split-K: 64x128 tiles, 512 blocks, all 32 steps; bias fused; writes out
// directly. All operands (Csel 1.6MB, Wo splits 4MB, invsel 1MB) are
// L2-resident, so half-height tiles carry no HBM re-fetch hazard.
struct OselArgs {
  const short* X;
  const short* Wa; const short* Wb;
  const float* bias;
  float* C;
  const int* invsel;
};

__global__ __launch_bounds__(256, 3) void gemm_osel_k(OselArgs ar) {
  __shared__ short As[64*64];    // 8 KB
  __shared__ short Bs[128*64];   // 16 KB
  __shared__ int utbl[1024];     // 4 KB
  const int fid = blockIdx.x;               // 0..511
  const int xcd = fid & 7, jj = fid >> 3;   // jj 0..63
  const int o = (xcd << 6) + jj;            // 0..511, XCD-chunked
  const int bx = o & 7, by = o >> 3;        // bx 0..7, by 0..63
  const int tid = threadIdx.x;
  const int wv = tid >> 6, L = tid & 63;
  const int lr = L & 15, lg = L >> 4;
  const int n0 = bx << 7, m0 = by << 6;
  const int wm = (wv >> 1) << 5, wn = (wv & 1) << 6;
  const int sr = tid >> 3, ssl = tid & 7;
  const int b2 = by >> 5;                   // batch

  #pragma unroll
  for (int e = 0; e < 4; ++e) {
    const int idx = (tid << 2) + e;             // 0..1023
    const int row = idx >> 4, h = idx & 15;
    utbl[idx] = ar.invsel[((((size_t)b2 << 4) + h) << 11) + ((m0 + row) & (NL - 1))];
  }
  __syncthreads();

  f32x4 acc[2][4];
  #pragma unroll
  for (int i = 0; i < 2; ++i)
    #pragma unroll
    for (int j = 0; j < 4; ++j) acc[i][j] = (f32x4){0.f,0.f,0.f,0.f};

  for (int step = 0; step < 32; ++step) {
    const int c = step >> 4, kk = (step & 15) << 6;
    const short* Wg = c ? ar.Wb : ar.Wa;        // c0:(Csel,Woa) c1:(Csel,Wob)
    #pragma unroll
    for (int j = 0; j < 2; ++j) {
      const int row = (j << 5) + sr;
      const int slot = (ssl ^ (row & 7)) << 3;
      const int h = step & 15;                  // one head per 64-wide step
      const int u = utbl[(row << 4) + h];
      gload16(ar.X + (((size_t)((b2 << 4) + h) * NUP + u) << 6) + slot,
              As + (j << 11) + (tid << 3));
    }
    #pragma unroll
    for (int j = 0; j < 4; ++j) {
      const int row = (j << 5) + sr;
      const int slot = (ssl ^ (row & 7)) << 3;
      gload16(Wg + (size_t)(n0 + row) * NDM + kk + slot, Bs + (j << 11) + (tid << 3));
    }
    __syncthreads();
    #pragma unroll
    for (int c2 = 0; c2 < 2; ++c2) {
      const int sl = (((c2 << 2) + lg) ^ (lr & 7)) << 3;
      bf16x8 af[2], bfr[4];
      #pragma unroll
      for (int t = 0; t < 2; ++t)
        af[t] = *(const bf16x8*)(As + ((wm + (t << 4) + lr) << 6) + sl);
      #pragma unroll
      for (int t = 0; t < 4; ++t)
        bfr[t] = *(const bf16x8*)(Bs + ((wn + (t << 4) + lr) << 6) + sl);
      #pragma unroll
      for (int mt = 0; mt < 2; ++mt)
        #pragma unroll
        for (int nt = 0; nt < 4; ++nt)
          acc[mt][nt] = __builtin_amdgcn_mfma_f32_16x16x32_bf16(bfr[nt], af[mt], acc[mt][nt], 0, 0, 0);
    }
    __syncthreads();
  }

  #pragma unroll
  for (int nt = 0; nt < 4; ++nt) {
    const int n = n0 + wn + (nt << 4) + (lg << 2);
    const float4 b4 = *(const float4*)(ar.bias + n);
    #pragma unroll
    for (int mt = 0; mt < 2; ++mt) {
      f32x4 a = acc[mt][nt];
      a[0] += b4.x; a[1] += b4.y; a[2] += b4.z; a[3] += b4.w;
      const int m = m0 + wm + (mt << 4) + lr;
      *(f32x4*)(ar.C + ((size_t)m << 10) + n) = a;
    }
  }
}

// ---------------------------------------------------------------- launch
extern "C" void kernel_launch(void* const* d_in, const int* in_sizes, int n_in,
                              void* d_out, int out_size, void* d_ws, size_t ws_size,
                              hipStream_t stream)
{
  (void)in_sizes; (void)n_in; (void)out_size; (void)ws_size;
  const float* queries = (const float*)d_in[0];
  const float* keys    = (const float*)d_in[1];
  const float* values  = (const float*)d_in[2];
  const float* Wq = (const float*)d_in[3];  const float* bq = (const float*)d_in[4];
  const float* Wk = (const float*)d_in[5];  const float* bk = (const float*)d_in[6];
  const float* Wv = (const float*)d_in[7];  const float* bv = (const float*)d_in[8];
  const float* Wo = (const float*)d_in[9];  const float* bo = (const float*)d_in[10];
  float* out = (float*)d_out;

  char* base = (char*)d_ws;
  #define MB(x) ((size_t)(x) << 20)

  short* Qa   = (short*)(base + MB(0));    // queries split a (dead after mega)
  short* Qb2  = (short*)(base + MB(8));    // queries split b
  short* Ka   = (short*)(base + MB(16));   // keys split a (dead after mega)
  short* Kb2  = (short*)(base + MB(24));
  short* Kbf  = (short*)(base + MB(32));   // written by mega K epilogue
  short* Vbf  = (short*)(base + MB(40));   // -> Csel after mega
  short* Qbf  = (short*)(base + MB(48));   // written by mega Q epilogue
  short* Vt   = (short*)(base + MB(56));   // written by mega V epilogue
  short* Wqa  = (short*)(base + MB(64));
  short* Wqb  = (short*)(base + MB(66));
  short* Wka  = (short*)(base + MB(68));
  short* Wkb  = (short*)(base + MB(70));
  short* Wvbf = (short*)(base + MB(72));
  short* Woa  = (short*)(base + MB(74));
  short* Wob  = (short*)(base + MB(76));
  char* sm = base + MB(78);
  double* kpart  = (double*)sm;  sm += 524288;    // [32][32][64] f64
  float*  wt     = (float*)sm;   sm += 131072;    // [32][1024] f32
  double* s0     = (double*)sm;  sm += 512;
  float*  sqv    = (float*)sm;   sm += 262144;    // [32][2048] f32
  float*  msb    = (float*)sm;   sm += 262144;
  int*    sel    = (int*)sm;     sm += 65536;
  int*    invsel = (int*)sm;     sm += 262144;

  // time-multiplexed aliases
  short* Csel = Vbf;                        // 1.625 MiB, after mega

  // ---- 1: all splits in one launch (inputs + weights)
  {
    SplitArgs a;
    a.d[0] = {queries, Qa, Qb2, nullptr, 2, 2048};
    a.d[1] = {keys,    Ka, Kb2, nullptr, 2, 2048};
    a.d[2] = {values,  Vbf, nullptr, nullptr, 1, 2048};
    a.d[3] = {Wq, Wqa, Wqb, nullptr, 2, 512};
    a.d[4] = {Wk, Wka, Wkb, nullptr, 2, 512};
    a.d[5] = {Wv, Wvbf, nullptr, nullptr, 1, 512};
    a.d[6] = {Wo, Woa, Wob, nullptr, 2, 512};
    msplit_k<<<dim3(2048,1,7), 256, 0, stream>>>(a);
  }
  // ---- 2: balanced mega GEMM, full tiles: Q(48, fused bf16+|q|^2 epilogue)
  //         + K(48, fused norm/kbar) + V(16, fused transpose); 768 blocks
  {
    GemmArgs g;
    g.d[0] = {{Qa,Qb2},  {Wqa,Wqb},   bq, Qbf, nullptr, sqv,     0, 48, 3};
    g.d[1] = {{Ka,Kb2},  {Wka,Wkb},   bk, Kbf, kpart,   nullptr, 0, 48, 1};
    g.d[2] = {{Vbf,Vbf}, {Wvbf,Wvbf}, bv, Vt,  nullptr, nullptr, 0, 16, 2};
    gemm_mega_k<<<768, 256, 0, stream>>>(g);
  }
  // ---- 3-5: ranking chain
  wtilde_k<<<dim3(NBH,4), 256, 0, stream>>>(Wq, bq, kpart, wt, s0);
  dotqms_k<<<NROWS, 256, 0, stream>>>(queries, sqv, wt, s0, msb);
  select_rank_k<<<NBH*8, 256, 0, stream>>>(msb, sel, invsel);

  // ---- 6: fused attention (bf16 Q gather; single bf16 Csel; pad rows zeroed)
  fattn_k<<<MTOT/32, 512, 0, stream>>>(Qbf, sel, Kbf, Vt, Csel);

  // ---- 7: output projection, no split-K, bias fused; writes out directly
  {
    OselArgs oa = {Csel, Woa, Wob, bo, out, invsel};
    gemm_osel_k<<<512, 256, 0, stream>>>(oa);
  }
}

// Round 17
// 212.791 us; speedup vs baseline: 1.3220x; 1.0550x over previous
//
#include <hip/hip_runtime.h>
#include <math.h>

// Problem constants (fixed by setup_inputs)
#define NB 2
#define NL 2048
#define NH 16
#define ND 64
#define NDM 1024
#define NU 409                  // max(1, 2048 // 5)
#define NUP 416                 // NU padded to multiple of 32; 416 = 26*16 = 13*32
#define NBH (NB*NH)             // 32
#define NROWS (NB*NL)           // 4096
#define NRTOT (NB*NH*NL)        // 65536
#define MTOT (NBH*NUP)          // 13312

typedef short bf16x8 __attribute__((ext_vector_type(8)));
typedef short bf16x4 __attribute__((ext_vector_type(4)));
typedef float f32x4  __attribute__((ext_vector_type(4)));

__device__ __forceinline__ short f2bf(float x) {   // RNE f32 -> bf16
  unsigned u = __float_as_uint(x);
  return (short)((u + 0x7FFFu + ((u >> 16) & 1u)) >> 16);
}
__device__ __forceinline__ float bf2f(short s) {
  return __uint_as_float(((unsigned)(unsigned short)s) << 16);
}

__device__ __forceinline__ void gload16(const short* g, short* l) {
  __builtin_amdgcn_global_load_lds(
      (const __attribute__((address_space(1))) void*)g,
      (__attribute__((address_space(3))) void*)l, 16, 0, 0);
}

// ---------------------------------------------------------------- multi-tensor f32 -> bf16 splits
struct SplitDesc { const float* in; short* a; short* b; short* c; int nc; int nblk; };
struct SplitArgs { SplitDesc d[7]; };

__global__ __launch_bounds__(256) void msplit_k(SplitArgs args) {
  const SplitDesc d = args.d[blockIdx.z];
  if ((int)blockIdx.x >= d.nblk) return;
  const size_t i = (size_t)blockIdx.x * 256 + threadIdx.x;
  const float4 x0 = ((const float4*)d.in)[2*i];
  const float4 x1 = ((const float4*)d.in)[2*i + 1];
  float x[8] = {x0.x,x0.y,x0.z,x0.w, x1.x,x1.y,x1.z,x1.w};
  bf16x8 va, vb;
  #pragma unroll
  for (int j = 0; j < 8; ++j) {
    const short A = f2bf(x[j]);
    va[j] = A;
    vb[j] = f2bf(x[j] - bf2f(A));
  }
  *(bf16x8*)(d.a + 8*i) = va;
  if (d.nc >= 2) *(bf16x8*)(d.b + 8*i) = vb;
}

// ---------------------------------------------------------------- mega projection GEMM (Q/K/V), full 128x128 tiles
// BK=64, 4 waves 2x2, wave 64x64 = 4x4 16x16 frags.
// chunk pairs (c=step>>4): c0 (a,a), c1 (a,b), c2 (b,a)
// LDS: linear dest for global_load_lds; SOURCE k-slot pre-swizzled s^=(row&7);
// fragment reads apply the same XOR (rule 21).
// 768 blocks; fid&7 = XCD, jd%3 = desc -> each CU hosts {Q,K,V}, equal work.
// mode 1: fused K epilogue: bias + row-norm -> Kbf bf16 + f64 kbar partials
// mode 2: fused V epilogue: +bias, LDS transpose, coalesced bf16 Vt (bh,d,l)
// mode 3: fused Q epilogue: bias -> Qbf bf16 (bh,l,d) + row |q|^2 f32 (sqv)
struct GemmDesc {
  const short* X[2];
  const short* W[2];
  const float* bias;
  short* KbfVt;         // mode 1: Kbf; mode 2: Vt; mode 3: Qbf
  double* kpart;        // mode 1: [bh][32][64] f64
  float* sq;            // mode 3: [bh][2048] f32
  int sbeg, send;       // step range; one step = 64 k-elems; chunk = step>>4
  int mode;
};
struct GemmArgs { GemmDesc d[3]; };

__global__ __launch_bounds__(256, 3) void gemm_mega_k(GemmArgs args) {
  __shared__ short As[128*64];   // 16 KB
  __shared__ short Bs[128*64];   // 16 KB
  const int fid = blockIdx.x;
  const int xcd = fid & 7, jd = fid >> 3;   // jd 0..95
  const int s = jd % 3, jj = jd / 3;        // desc s; tile jj 0..31
  const int tile = (xcd << 5) + jj;         // 0..255
  const int bx = tile & 7, by = tile >> 3;
  const GemmDesc d = args.d[s];
  const int tid = threadIdx.x;
  const int wv = tid >> 6, L = tid & 63;
  const int lr = L & 15, lg = L >> 4;
  const int n0 = bx << 7, m0 = by << 7;
  const int wm = (wv >> 1) << 6, wn = (wv & 1) << 6;
  const int sr = tid >> 3, ssl = tid & 7;

  f32x4 acc[4][4];
  #pragma unroll
  for (int i = 0; i < 4; ++i)
    #pragma unroll
    for (int j = 0; j < 4; ++j) acc[i][j] = (f32x4){0.f,0.f,0.f,0.f};

  for (int step = d.sbeg; step < d.send; ++step) {
    const int c = step >> 4, kk = (step & 15) << 6;
    const short *Xg, *Wg;
    switch (c) {
      case 0:  Xg = d.X[0]; Wg = d.W[0]; break;
      case 1:  Xg = d.X[0]; Wg = d.W[1]; break;
      default: Xg = d.X[1]; Wg = d.W[0]; break;
    }
    #pragma unroll
    for (int j = 0; j < 4; ++j) {
      const int row = (j << 5) + sr;
      const int slot = (ssl ^ (row & 7)) << 3;   // pre-swizzled k-slot
      gload16(Xg + (size_t)(m0 + row) * NDM + kk + slot, As + (j << 11) + (tid << 3));
      gload16(Wg + (size_t)(n0 + row) * NDM + kk + slot, Bs + (j << 11) + (tid << 3));
    }
    __syncthreads();
    #pragma unroll
    for (int c2 = 0; c2 < 2; ++c2) {
      const int sl = (((c2 << 2) + lg) ^ (lr & 7)) << 3;
      bf16x8 af[4], bfr[4];
      #pragma unroll
      for (int t = 0; t < 4; ++t) {
        af[t]  = *(const bf16x8*)(As + ((wm + (t << 4) + lr) << 6) + sl);
        bfr[t] = *(const bf16x8*)(Bs + ((wn + (t << 4) + lr) << 6) + sl);
      }
      #pragma unroll
      for (int mt = 0; mt < 4; ++mt)
        #pragma unroll
        for (int nt = 0; nt < 4; ++nt)
          acc[mt][nt] = __builtin_amdgcn_mfma_f32_16x16x32_bf16(bfr[nt], af[mt], acc[mt][nt], 0, 0, 0);
    }
    __syncthreads();
  }

  if (d.mode == 1) {
    // ---- fused K epilogue: k = acc + bias; |k| via shfl over lg groups;
    //      Kbf bf16 store; f64 kbar partials.
    const int b2 = by >> 4;
    const int hw = (bx << 1) + (wv & 1);          // head of this wave
    const int bh = (b2 << 4) + hw;
    const int seg = ((by & 15) << 1) + (wv >> 1); // 64-row segment within bh
    float kv[4][4][4];
    double inv[4];
    #pragma unroll
    for (int mt = 0; mt < 4; ++mt) {
      float ss = 0.f;
      #pragma unroll
      for (int nt = 0; nt < 4; ++nt) {
        const int n = n0 + wn + (nt << 4) + (lg << 2);
        const float4 b4 = *(const float4*)(d.bias + n);
        kv[mt][nt][0] = acc[mt][nt][0] + b4.x;
        kv[mt][nt][1] = acc[mt][nt][1] + b4.y;
        kv[mt][nt][2] = acc[mt][nt][2] + b4.z;
        kv[mt][nt][3] = acc[mt][nt][3] + b4.w;
        #pragma unroll
        for (int j = 0; j < 4; ++j) ss += kv[mt][nt][j] * kv[mt][nt][j];
      }
      ss += __shfl_xor(ss, 16);
      ss += __shfl_xor(ss, 32);
      inv[mt] = 1.0 / sqrt((double)ss);
    }
    #pragma unroll
    for (int mt = 0; mt < 4; ++mt) {
      const int l = (m0 + wm + (mt << 4) + lr) & (NL - 1);
      short* kp = d.KbfVt + (((size_t)bh * NL + l) << 6);
      #pragma unroll
      for (int nt = 0; nt < 4; ++nt) {
        const int dd = (nt << 4) + (lg << 2);
        bf16x4 o;
        #pragma unroll
        for (int j = 0; j < 4; ++j) o[j] = f2bf(kv[mt][nt][j]);
        *(bf16x4*)(kp + dd) = o;
      }
    }
    #pragma unroll
    for (int nt = 0; nt < 4; ++nt) {
      double p[4];
      #pragma unroll
      for (int j = 0; j < 4; ++j) {
        p[j] = 0.0;
        #pragma unroll
        for (int mt = 0; mt < 4; ++mt) p[j] += (double)kv[mt][nt][j] * inv[mt];
        p[j] += __shfl_xor(p[j], 1);
        p[j] += __shfl_xor(p[j], 2);
        p[j] += __shfl_xor(p[j], 4);
        p[j] += __shfl_xor(p[j], 8);
      }
      if (lr == 0) {
        const int dd = (nt << 4) + (lg << 2);
        double* kp = d.kpart + ((((size_t)bh << 5) + seg) << 6) + dd;
        kp[0] = p[0]; kp[1] = p[1]; kp[2] = p[2]; kp[3] = p[3];
      }
    }
  } else if (d.mode == 3) {
    // ---- fused Q epilogue: q = acc + bias; |q|^2 via shfl; Qbf bf16 + sqv f32
    const int b2 = by >> 4;
    const int hw = (bx << 1) + (wv & 1);
    const int bh = (b2 << 4) + hw;
    #pragma unroll
    for (int mt = 0; mt < 4; ++mt) {
      float kv[4][4];
      float ss = 0.f;
      #pragma unroll
      for (int nt = 0; nt < 4; ++nt) {
        const int n = n0 + wn + (nt << 4) + (lg << 2);
        const float4 b4 = *(const float4*)(d.bias + n);
        kv[nt][0] = acc[mt][nt][0] + b4.x;
        kv[nt][1] = acc[mt][nt][1] + b4.y;
        kv[nt][2] = acc[mt][nt][2] + b4.z;
        kv[nt][3] = acc[mt][nt][3] + b4.w;
        #pragma unroll
        for (int j = 0; j < 4; ++j) ss += kv[nt][j] * kv[nt][j];
      }
      ss += __shfl_xor(ss, 16);
      ss += __shfl_xor(ss, 32);
      const int l = (m0 + wm + (mt << 4) + lr) & (NL - 1);
      if (lg == 0) d.sq[((size_t)bh << 11) + l] = ss;
      short* qp = d.KbfVt + (((size_t)bh * NL + l) << 6);
      #pragma unroll
      for (int nt = 0; nt < 4; ++nt) {
        const int dd = (nt << 4) + (lg << 2);
        bf16x4 o;
        #pragma unroll
        for (int j = 0; j < 4; ++j) o[j] = f2bf(kv[nt][j]);
        *(bf16x4*)(qp + dd) = o;
      }
    }
  } else {
    // ---- fused V epilogue: +bias -> bf16 into LDS T(n,m) (XOR col swizzle),
    //      then coalesced 128B-contiguous stores into Vt[bh][d][l].
    #pragma unroll
    for (int nt = 0; nt < 4; ++nt) {
      const int nl = wn + (nt << 4) + (lg << 2);
      const float4 b4 = *(const float4*)(d.bias + n0 + nl);
      #pragma unroll
      for (int j2 = 0; j2 < 4; ++j2) {
        const int row = nl + j2;
        short* Tp = (row & 64) ? Bs : As;
        const int rr = row & 63;
        const float bj = (j2 == 0) ? b4.x : (j2 == 1) ? b4.y : (j2 == 2) ? b4.z : b4.w;
        const int sw = (row & 7) << 3;
        #pragma unroll
        for (int mt = 0; mt < 4; ++mt) {
          const int m = wm + (mt << 4) + lr;
          Tp[rr * 128 + (m ^ sw)] = f2bf(acc[mt][nt][j2] + bj);
        }
      }
    }
    __syncthreads();
    {
      const int r = tid >> 1, seg2 = tid & 1;
      const short* Tp = (r & 64) ? Bs : As;
      const int rr = r & 63, sw = (r & 7) << 3;
      const int ngl = n0 + r, h = ngl >> 6, dd2 = ngl & 63;
      const int bb = m0 >> 11, ll = m0 & (NL - 1);
      short* dst = d.KbfVt + (((size_t)((((bb << 4) + h) << 6) + dd2)) << 11) + ll + (seg2 << 6);
      #pragma unroll
      for (int i = 0; i < 8; ++i)
        *(bf16x8*)(dst + (i << 3)) =
            *(const bf16x8*)(Tp + rr * 128 + (((seg2 << 6) + (i << 3)) ^ sw));
    }
  }
}

// ---------------------------------------------------------------- wtilde (+inline kbar reduce): wt[bh][j] f32, s0[bh] f64
__global__ __launch_bounds__(256) void wtilde_k(const float* __restrict__ Wq,
                                                const float* __restrict__ bq,
                                                const double* __restrict__ kpart,
                                                float* __restrict__ wt,
                                                double* __restrict__ s0) {
  __shared__ double kb[64];
  const int bh = blockIdx.x, h = bh & 15;
  const int tid = threadIdx.x;
  if (tid < 64) {
    double s = 0.0;
    #pragma unroll
    for (int seg = 0; seg < 32; ++seg)
      s += kpart[((((size_t)bh << 5) + seg) << 6) + tid];
    kb[tid] = s * (1.0 / NL);
  }
  __syncthreads();
  const int j = (blockIdx.y << 8) + tid;
  double a = 0.0;
  #pragma unroll 8
  for (int d = 0; d < 64; ++d)
    a += (double)Wq[(((size_t)((h << 6) + d)) << 10) + j] * kb[d];
  wt[((size_t)bh << 10) + j] = (float)a;
  if (blockIdx.y == 0 && tid < 64) {
    double p = (double)bq[(h << 6) + tid] * kb[tid];
    #pragma unroll
    for (int off = 32; off > 0; off >>= 1) p += __shfl_xor(p, off);
    if (tid == 0) s0[bh] = p;
  }
}

// ---------------------------------------------------------------- fused dotq+msq: ms[bh][l] = (x.wt + s0)/sqrt(sqv)
__global__ __launch_bounds__(256) void dotqms_k(const float* __restrict__ x,
                                                const float* __restrict__ sqv,
                                                const float* __restrict__ wt,
                                                const double* __restrict__ s0,
                                                float* __restrict__ ms) {
  __shared__ float xs[1024];
  __shared__ double sm[16][16];
  const int r = blockIdx.x, b = r >> 11, l = r & (NL - 1);
  const int tid = threadIdx.x;
  ((float4*)xs)[tid] = ((const float4*)(x + ((size_t)r << 10)))[tid];
  __syncthreads();
  const int h = tid >> 4, t = tid & 15;
  const float* w = wt + ((size_t)((b << 4) + h) << 10);
  double a = 0.0;
  #pragma unroll 8
  for (int i = 0; i < 64; ++i) {
    const int j = t + (i << 4);
    a += (double)xs[j] * (double)w[j];
  }
  sm[h][t] = a;
  __syncthreads();
  if (tid < 16) {
    double s = 0.0;
    #pragma unroll
    for (int t2 = 0; t2 < 16; ++t2) s += sm[tid][t2];
    const size_t ro = (((size_t)(b << 4) + tid) << 11) + l;
    ms[ro] = (float)((s + s0[(b << 4) + tid]) / sqrt((double)sqv[ro]));
  }
}

// ---------------------------------------------------------------- rank-based top-NU selection (+ inverse map; pad -> NU)
__global__ __launch_bounds__(256) void select_rank_k(const float* __restrict__ ms,
                                                     int* __restrict__ sel,
                                                     int* __restrict__ invsel) {
  __shared__ unsigned long long keys[NL];
  const int bh = blockIdx.x >> 3, seg = blockIdx.x & 7;
  const int tid = threadIdx.x;
  for (int l = tid; l < NL; l += 256) {
    unsigned u = __float_as_uint(ms[(size_t)bh * NL + l]);
    u = (u & 0x80000000u) ? ~u : (u | 0x80000000u);   // order-preserving map
    keys[l] = ((unsigned long long)u << 32) | (unsigned)(NL - 1 - l);
  }
  __syncthreads();
  const int r = (seg << 8) + tid;
  const unsigned long long mine = keys[r];
  int cnt = 0;
  #pragma unroll 8
  for (int l = 0; l < NL; ++l) cnt += (keys[l] > mine) ? 1 : 0;
  if (cnt < NU) sel[bh*NU + cnt] = r;
  invsel[(size_t)bh * NL + r] = (cnt < NU) ? cnt : NU;  // NU = zeroed pad row
}

// ---------------------------------------------------------------- fused attention; bf16 Q gather; single bf16 Csel out
__global__ __launch_bounds__(512) void fattn_k(const short* __restrict__ Qbf,
                                               const int* __restrict__ sel,
                                               const short* __restrict__ Kbf,
                                               const short* __restrict__ Vt,
                                               short* __restrict__ Csel) {
  __shared__ short S[32*2048];        // 128 KB, row stride 4096 B
  __shared__ float inv_s[32];
  int bid = blockIdx.x;
  bid = (bid & 7) * 52 + (bid >> 3);  // 416 = 8*52 XCD chunks
  const int m0 = bid << 5;
  const int bh = m0 / NUP;
  const int u0 = m0 - bh * NUP;
  const int tid = threadIdx.x;
  const int w = tid >> 6, L = tid & 63;
  const int lr = L & 15, lg = L >> 4;

  // ---- Q fragments gathered from bf16 Qbf via sel (pad rows read row 0, discarded)
  bf16x8 qf[2][2];
  #pragma unroll
  for (int mt = 0; mt < 2; ++mt) {
    const int u = u0 + mt*16 + lr;
    const int lq = (u < NU) ? sel[bh*NU + u] : 0;
    const short* qp = Qbf + (((size_t)bh*NL + lq) << 6) + lg*8;
    qf[mt][0] = *(const bf16x8*)qp;
    qf[mt][1] = *(const bf16x8*)(qp + 32);
  }
  const int nb = w << 8;
  const short* kb0 = Kbf + (((size_t)bh*NL + nb + lr) << 6) + lg*8;
  __builtin_amdgcn_s_setprio(1);      // T5: favor MFMA-issuing waves
  #pragma unroll 4
  for (int nt = 0; nt < 16; ++nt) {
    const short* kp = kb0 + ((size_t)nt << 10);
    const bf16x8 kf0 = *(const bf16x8*)kp;
    const bf16x8 kf1 = *(const bf16x8*)(kp + 32);
    #pragma unroll
    for (int mt = 0; mt < 2; ++mt) {
      f32x4 a = {0.f,0.f,0.f,0.f};
      a = __builtin_amdgcn_mfma_f32_16x16x32_bf16(kf0, qf[mt][0], a, 0, 0, 0);
      a = __builtin_amdgcn_mfma_f32_16x16x32_bf16(kf1, qf[mt][1], a, 0, 0, 0);
      const int m = mt*16 + lr;
      bf16x4 o;
      #pragma unroll
      for (int r = 0; r < 4; ++r) o[r] = f2bf(a[r] * 0.125f);
      const int byteoff = (m << 12) + ((((nb + nt*16 + lg*4) << 1)) ^ ((m & 7) << 4));
      *(bf16x4*)((char*)S + byteoff) = o;
    }
  }
  __builtin_amdgcn_s_setprio(0);
  __syncthreads();

  #pragma unroll
  for (int j = 0; j < 4; ++j) {
    const int R = (w << 2) + j;
    char* rowp = (char*)S + (R << 12);
    const int sw = (R & 7) << 4;
    bf16x8 v[4];
    #pragma unroll
    for (int i = 0; i < 4; ++i)
      v[i] = *(const bf16x8*)(rowp + (((L << 6) + (i << 4)) ^ sw));
    float f[32];
    #pragma unroll
    for (int i = 0; i < 4; ++i)
      #pragma unroll
      for (int e = 0; e < 8; ++e) f[i*8+e] = bf2f(v[i][e]);
    float mx = f[0];
    #pragma unroll
    for (int i = 1; i < 32; ++i) mx = fmaxf(mx, f[i]);
    #pragma unroll
    for (int off = 32; off > 0; off >>= 1) mx = fmaxf(mx, __shfl_xor(mx, off));
    float sum = 0.f;
    #pragma unroll
    for (int i = 0; i < 32; ++i) { f[i] = __expf(f[i] - mx); sum += f[i]; }
    #pragma unroll
    for (int off = 32; off > 0; off >>= 1) sum += __shfl_xor(sum, off);
    bf16x8 p[4];
    #pragma unroll
    for (int i = 0; i < 4; ++i)
      #pragma unroll
      for (int e = 0; e < 8; ++e) p[i][e] = f2bf(f[i*8+e]);
    #pragma unroll
    for (int i = 0; i < 4; ++i)
      *(bf16x8*)(rowp + (((L << 6) + (i << 4)) ^ sw)) = p[i];
    if (L == 0) inv_s[R] = 1.f / sum;
  }
  __syncthreads();

  {
    const int mt = w & 1, dt = w >> 1;
    const int m = mt*16 + lr;
    const char* arow = (const char*)S + (m << 12);
    const int sw = (m & 7) << 4;
    const short* vrow = Vt + (((size_t)bh*ND + dt*16 + lr) << 11) + lg*8;
    f32x4 acc0 = {0.f,0.f,0.f,0.f}, acc1 = {0.f,0.f,0.f,0.f};
    __builtin_amdgcn_s_setprio(1);    // T5
    #pragma unroll 2
    for (int k0 = 0; k0 < NL; k0 += 64) {
      const bf16x8 p0 = *(const bf16x8*)(arow + ((((k0 + lg*8) << 1)) ^ sw));
      const bf16x8 p1 = *(const bf16x8*)(arow + ((((k0 + 32 + lg*8) << 1)) ^ sw));
      const bf16x8 v0 = *(const bf16x8*)(vrow + k0);
      const bf16x8 v1 = *(const bf16x8*)(vrow + k0 + 32);
      acc0 = __builtin_amdgcn_mfma_f32_16x16x32_bf16(p0, v0, acc0, 0, 0, 0);
      acc1 = __builtin_amdgcn_mfma_f32_16x16x32_bf16(p1, v1, acc1, 0, 0, 0);
    }
    __builtin_amdgcn_s_setprio(0);
    const int ub = u0 + mt*16 + (lg << 2);
    #pragma unroll
    for (int r = 0; r < 4; ++r) {
      float val = (acc0[r] + acc1[r]) * inv_s[mt*16 + (lg << 2) + r];
      if (ub + r >= NU) val = 0.f;                 // zero pad rows (incl. row NU)
      const size_t off = (((size_t)m0 + mt*16 + (lg << 2) + r) << 6) + dt*16 + lr;
      Csel[off] = f2bf(val);
    }
  }
}

// ---------------------------------------------------------------- O projection GEMM (X gathered from Csel via invsel)
// Single W chunk (Wo bf16), 16 steps. 64x128 tiles, 512 blocks, bias fused,
// writes out directly. Operands (Csel 1.6MB, Wobf 2MB, invsel 1MB) L2-resident.
struct OselArgs {
  const short* X;
  const short* W;
  const float* bias;
  float* C;
  const int* invsel;
};

__global__ __launch_bounds__(256, 3) void gemm_osel_k(OselArgs ar) {
  __shared__ short As[64*64];    // 8 KB
  __shared__ short Bs[128*64];   // 16 KB
  __shared__ int utbl[1024];     // 4 KB
  const int fid = blockIdx.x;               // 0..511
  const int xcd = fid & 7, jj = fid >> 3;   // jj 0..63
  const int o = (xcd << 6) + jj;            // 0..511, XCD-chunked
  const int bx = o & 7, by = o >> 3;        // bx 0..7, by 0..63
  const int tid = threadIdx.x;
  const int wv = tid >> 6, L = tid & 63;
  const int lr = L & 15, lg = L >> 4;
  const int n0 = bx << 7, m0 = by << 6;
  const int wm = (wv >> 1) << 5, wn = (wv & 1) << 6;
  const int sr = tid >> 3, ssl = tid & 7;
  const int b2 = by >> 5;                   // batch

  #pragma unroll
  for (int e = 0; e < 4; ++e) {
    const int idx = (tid << 2) + e;             // 0..1023
    const int row = idx >> 4, h = idx & 15;
    utbl[idx] = ar.invsel[((((size_t)b2 << 4) + h) << 11) + ((m0 + row) & (NL - 1))];
  }
  __syncthreads();

  f32x4 acc[2][4];
  #pragma unroll
  for (int i = 0; i < 2; ++i)
    #pragma unroll
    for (int j = 0; j < 4; ++j) acc[i][j] = (f32x4){0.f,0.f,0.f,0.f};

  for (int step = 0; step < 16; ++step) {
    const int kk = step << 6;
    #pragma unroll
    for (int j = 0; j < 2; ++j) {
      const int row = (j << 5) + sr;
      const int slot = (ssl ^ (row & 7)) << 3;
      const int h = step & 15;                  // one head per 64-wide step
      const int u = utbl[(row << 4) + h];
      gload16(ar.X + (((size_t)((b2 << 4) + h) * NUP + u) << 6) + slot,
              As + (j << 11) + (tid << 3));
    }
    #pragma unroll
    for (int j = 0; j < 4; ++j) {
      const int row = (j << 5) + sr;
      const int slot = (ssl ^ (row & 7)) << 3;
      gload16(ar.W + (size_t)(n0 + row) * NDM + kk + slot, Bs + (j << 11) + (tid << 3));
    }
    __syncthreads();
    #pragma unroll
    for (int c2 = 0; c2 < 2; ++c2) {
      const int sl = (((c2 << 2) + lg) ^ (lr & 7)) << 3;
      bf16x8 af[2], bfr[4];
      #pragma unroll
      for (int t = 0; t < 2; ++t)
        af[t] = *(const bf16x8*)(As + ((wm + (t << 4) + lr) << 6) + sl);
      #pragma unroll
      for (int t = 0; t < 4; ++t)
        bfr[t] = *(const bf16x8*)(Bs + ((wn + (t << 4) + lr) << 6) + sl);
      #pragma unroll
      for (int mt = 0; mt < 2; ++mt)
        #pragma unroll
        for (int nt = 0; nt < 4; ++nt)
          acc[mt][nt] = __builtin_amdgcn_mfma_f32_16x16x32_bf16(bfr[nt], af[mt], acc[mt][nt], 0, 0, 0);
    }
    __syncthreads();
  }

  #pragma unroll
  for (int nt = 0; nt < 4; ++nt) {
    const int n = n0 + wn + (nt << 4) + (lg << 2);
    const float4 b4 = *(const float4*)(ar.bias + n);
    #pragma unroll
    for (int mt = 0; mt < 2; ++mt) {
      f32x4 a = acc[mt][nt];
      a[0] += b4.x; a[1] += b4.y; a[2] += b4.z; a[3] += b4.w;
      const int m = m0 + wm + (mt << 4) + lr;
      *(f32x4*)(ar.C + ((size_t)m << 10) + n) = a;
    }
  }
}

// ---------------------------------------------------------------- launch
extern "C" void kernel_launch(void* const* d_in, const int* in_sizes, int n_in,
                              void* d_out, int out_size, void* d_ws, size_t ws_size,
                              hipStream_t stream)
{
  (void)in_sizes; (void)n_in; (void)out_size; (void)ws_size;
  const float* queries = (const float*)d_in[0];
  const float* keys    = (const float*)d_in[1];
  const float* values  = (const float*)d_in[2];
  const float* Wq = (const float*)d_in[3];  const float* bq = (const float*)d_in[4];
  const float* Wk = (const float*)d_in[5];  const float* bk = (const float*)d_in[6];
  const float* Wv = (const float*)d_in[7];  const float* bv = (const float*)d_in[8];
  const float* Wo = (const float*)d_in[9];  const float* bo = (const float*)d_in[10];
  float* out = (float*)d_out;

  char* base = (char*)d_ws;
  #define MB(x) ((size_t)(x) << 20)

  short* Qa   = (short*)(base + MB(0));    // queries split a (dead after mega)
  short* Qb2  = (short*)(base + MB(8));    // queries split b
  short* Ka   = (short*)(base + MB(16));   // keys split a (dead after mega)
  short* Kb2  = (short*)(base + MB(24));
  short* Kbf  = (short*)(base + MB(32));   // written by mega K epilogue
  short* Vbf  = (short*)(base + MB(40));   // -> Csel after mega
  short* Qbf  = (short*)(base + MB(48));   // written by mega Q epilogue
  short* Vt   = (short*)(base + MB(56));   // written by mega V epilogue
  short* Wqa  = (short*)(base + MB(64));
  short* Wqb  = (short*)(base + MB(66));
  short* Wka  = (short*)(base + MB(68));
  short* Wkb  = (short*)(base + MB(70));
  short* Wvbf = (short*)(base + MB(72));
  short* Wobf = (short*)(base + MB(74));
  char* sm = base + MB(78);
  double* kpart  = (double*)sm;  sm += 524288;    // [32][32][64] f64
  float*  wt     = (float*)sm;   sm += 131072;    // [32][1024] f32
  double* s0     = (double*)sm;  sm += 512;
  float*  sqv    = (float*)sm;   sm += 262144;    // [32][2048] f32
  float*  msb    = (float*)sm;   sm += 262144;
  int*    sel    = (int*)sm;     sm += 65536;
  int*    invsel = (int*)sm;     sm += 262144;

  // time-multiplexed aliases
  short* Csel = Vbf;                        // 1.625 MiB, after mega

  // ---- 1: all splits in one launch (inputs + weights)
  {
    SplitArgs a;
    a.d[0] = {queries, Qa, Qb2, nullptr, 2, 2048};
    a.d[1] = {keys,    Ka, Kb2, nullptr, 2, 2048};
    a.d[2] = {values,  Vbf, nullptr, nullptr, 1, 2048};
    a.d[3] = {Wq, Wqa, Wqb, nullptr, 2, 512};
    a.d[4] = {Wk, Wka, Wkb, nullptr, 2, 512};
    a.d[5] = {Wv, Wvbf, nullptr, nullptr, 1, 512};
    a.d[6] = {Wo, Wobf, nullptr, nullptr, 1, 512};
    msplit_k<<<dim3(2048,1,7), 256, 0, stream>>>(a);
  }
  // ---- 2: balanced mega GEMM, full tiles: Q(48, fused bf16+|q|^2 epilogue)
  //         + K(48, fused norm/kbar) + V(16, fused transpose); 768 blocks
  {
    GemmArgs g;
    g.d[0] = {{Qa,Qb2},  {Wqa,Wqb},   bq, Qbf, nullptr, sqv,     0, 48, 3};
    g.d[1] = {{Ka,Kb2},  {Wka,Wkb},   bk, Kbf, kpart,   nullptr, 0, 48, 1};
    g.d[2] = {{Vbf,Vbf}, {Wvbf,Wvbf}, bv, Vt,  nullptr, nullptr, 0, 16, 2};
    gemm_mega_k<<<768, 256, 0, stream>>>(g);
  }
  // ---- 3-5: ranking chain
  wtilde_k<<<dim3(NBH,4), 256, 0, stream>>>(Wq, bq, kpart, wt, s0);
  dotqms_k<<<NROWS, 256, 0, stream>>>(queries, sqv, wt, s0, msb);
  select_rank_k<<<NBH*8, 256, 0, stream>>>(msb, sel, invsel);

  // ---- 6: fused attention (bf16 Q gather; single bf16 Csel; pad rows zeroed)
  fattn_k<<<MTOT/32, 512, 0, stream>>>(Qbf, sel, Kbf, Vt, Csel);

  // ---- 7: output projection, single Wo chunk, bias fused; writes out directly
  {
    OselArgs oa = {Csel, Wobf, bo, out, invsel};
    gemm_osel_k<<<512, 256, 0, stream>>>(oa);
  }
}

// Round 18
// 212.487 us; speedup vs baseline: 1.3239x; 1.0014x over previous
//
#include <hip/hip_runtime.h>
#include <math.h>

// Problem constants (fixed by setup_inputs)
#define NB 2
#define NL 2048
#define NH 16
#define ND 64
#define NDM 1024
#define NU 409                  // max(1, 2048 // 5)
#define NUP 416                 // NU padded to multiple of 32; 416 = 26*16 = 13*32
#define NBH (NB*NH)             // 32
#define NROWS (NB*NL)           // 4096
#define NRTOT (NB*NH*NL)        // 65536
#define MTOT (NBH*NUP)          // 13312

typedef short bf16x8 __attribute__((ext_vector_type(8)));
typedef short bf16x4 __attribute__((ext_vector_type(4)));
typedef float f32x4  __attribute__((ext_vector_type(4)));

__device__ __forceinline__ short f2bf(float x) {   // RNE f32 -> bf16
  unsigned u = __float_as_uint(x);
  return (short)((u + 0x7FFFu + ((u >> 16) & 1u)) >> 16);
}
__device__ __forceinline__ float bf2f(short s) {
  return __uint_as_float(((unsigned)(unsigned short)s) << 16);
}

__device__ __forceinline__ void gload16(const short* g, short* l) {
  __builtin_amdgcn_global_load_lds(
      (const __attribute__((address_space(1))) void*)g,
      (__attribute__((address_space(3))) void*)l, 16, 0, 0);
}

// ---------------------------------------------------------------- multi-tensor f32 -> bf16 splits
struct SplitDesc { const float* in; short* a; short* b; short* c; int nc; int nblk; };
struct SplitArgs { SplitDesc d[7]; };

__global__ __launch_bounds__(256) void msplit_k(SplitArgs args) {
  const SplitDesc d = args.d[blockIdx.z];
  if ((int)blockIdx.x >= d.nblk) return;
  const size_t i = (size_t)blockIdx.x * 256 + threadIdx.x;
  const float4 x0 = ((const float4*)d.in)[2*i];
  const float4 x1 = ((const float4*)d.in)[2*i + 1];
  float x[8] = {x0.x,x0.y,x0.z,x0.w, x1.x,x1.y,x1.z,x1.w};
  bf16x8 va, vb;
  #pragma unroll
  for (int j = 0; j < 8; ++j) {
    const short A = f2bf(x[j]);
    va[j] = A;
    vb[j] = f2bf(x[j] - bf2f(A));
  }
  *(bf16x8*)(d.a + 8*i) = va;
  if (d.nc >= 2) *(bf16x8*)(d.b + 8*i) = vb;
}

// ---------------------------------------------------------------- mega projection GEMM (Q/K/V), full 128x128 tiles
// BK=64, 4 waves 2x2, wave 64x64 = 4x4 16x16 frags.
// chunk pairs (c=step>>4): c0 (a,a), c1 (a,b), c2 (b,a)
// LDS: linear dest for global_load_lds; SOURCE k-slot pre-swizzled s^=(row&7);
// fragment reads apply the same XOR (rule 21).
// 768 blocks; fid&7 = XCD, jd%3 = desc -> each CU hosts {Q,K,V}, equal work.
// mode 1: fused K epilogue: bias + row-norm -> Kbf bf16 + f64 kbar partials
// mode 2: fused V epilogue: +bias, LDS transpose, coalesced bf16 Vt (bh,d,l)
// mode 3: fused Q epilogue: bias -> Qbf bf16 (bh,l,d) + row |q|^2 f32 (sqv)
struct GemmDesc {
  const short* X[2];
  const short* W[2];
  const float* bias;
  short* KbfVt;         // mode 1: Kbf; mode 2: Vt; mode 3: Qbf
  double* kpart;        // mode 1: [bh][32][64] f64
  float* sq;            // mode 3: [bh][2048] f32
  int sbeg, send;       // step range; one step = 64 k-elems; chunk = step>>4
  int mode;
};
struct GemmArgs { GemmDesc d[3]; };

__global__ __launch_bounds__(256, 3) void gemm_mega_k(GemmArgs args) {
  __shared__ short As[128*64];   // 16 KB
  __shared__ short Bs[128*64];   // 16 KB
  const int fid = blockIdx.x;
  const int xcd = fid & 7, jd = fid >> 3;   // jd 0..95
  const int s = jd % 3, jj = jd / 3;        // desc s; tile jj 0..31
  const int tile = (xcd << 5) + jj;         // 0..255
  const int bx = tile & 7, by = tile >> 3;
  const GemmDesc d = args.d[s];
  const int tid = threadIdx.x;
  const int wv = tid >> 6, L = tid & 63;
  const int lr = L & 15, lg = L >> 4;
  const int n0 = bx << 7, m0 = by << 7;
  const int wm = (wv >> 1) << 6, wn = (wv & 1) << 6;
  const int sr = tid >> 3, ssl = tid & 7;

  f32x4 acc[4][4];
  #pragma unroll
  for (int i = 0; i < 4; ++i)
    #pragma unroll
    for (int j = 0; j < 4; ++j) acc[i][j] = (f32x4){0.f,0.f,0.f,0.f};

  for (int step = d.sbeg; step < d.send; ++step) {
    const int c = step >> 4, kk = (step & 15) << 6;
    const short *Xg, *Wg;
    switch (c) {
      case 0:  Xg = d.X[0]; Wg = d.W[0]; break;
      case 1:  Xg = d.X[0]; Wg = d.W[1]; break;
      default: Xg = d.X[1]; Wg = d.W[0]; break;
    }
    #pragma unroll
    for (int j = 0; j < 4; ++j) {
      const int row = (j << 5) + sr;
      const int slot = (ssl ^ (row & 7)) << 3;   // pre-swizzled k-slot
      gload16(Xg + (size_t)(m0 + row) * NDM + kk + slot, As + (j << 11) + (tid << 3));
      gload16(Wg + (size_t)(n0 + row) * NDM + kk + slot, Bs + (j << 11) + (tid << 3));
    }
    __syncthreads();
    #pragma unroll
    for (int c2 = 0; c2 < 2; ++c2) {
      const int sl = (((c2 << 2) + lg) ^ (lr & 7)) << 3;
      bf16x8 af[4], bfr[4];
      #pragma unroll
      for (int t = 0; t < 4; ++t) {
        af[t]  = *(const bf16x8*)(As + ((wm + (t << 4) + lr) << 6) + sl);
        bfr[t] = *(const bf16x8*)(Bs + ((wn + (t << 4) + lr) << 6) + sl);
      }
      #pragma unroll
      for (int mt = 0; mt < 4; ++mt)
        #pragma unroll
        for (int nt = 0; nt < 4; ++nt)
          acc[mt][nt] = __builtin_amdgcn_mfma_f32_16x16x32_bf16(bfr[nt], af[mt], acc[mt][nt], 0, 0, 0);
    }
    __syncthreads();
  }

  if (d.mode == 1) {
    // ---- fused K epilogue: k = acc + bias; |k| via shfl over lg groups;
    //      Kbf bf16 store; f64 kbar partials.
    const int b2 = by >> 4;
    const int hw = (bx << 1) + (wv & 1);          // head of this wave
    const int bh = (b2 << 4) + hw;
    const int seg = ((by & 15) << 1) + (wv >> 1); // 64-row segment within bh
    float kv[4][4][4];
    double inv[4];
    #pragma unroll
    for (int mt = 0; mt < 4; ++mt) {
      float ss = 0.f;
      #pragma unroll
      for (int nt = 0; nt < 4; ++nt) {
        const int n = n0 + wn + (nt << 4) + (lg << 2);
        const float4 b4 = *(const float4*)(d.bias + n);
        kv[mt][nt][0] = acc[mt][nt][0] + b4.x;
        kv[mt][nt][1] = acc[mt][nt][1] + b4.y;
        kv[mt][nt][2] = acc[mt][nt][2] + b4.z;
        kv[mt][nt][3] = acc[mt][nt][3] + b4.w;
        #pragma unroll
        for (int j = 0; j < 4; ++j) ss += kv[mt][nt][j] * kv[mt][nt][j];
      }
      ss += __shfl_xor(ss, 16);
      ss += __shfl_xor(ss, 32);
      inv[mt] = 1.0 / sqrt((double)ss);
    }
    #pragma unroll
    for (int mt = 0; mt < 4; ++mt) {
      const int l = (m0 + wm + (mt << 4) + lr) & (NL - 1);
      short* kp = d.KbfVt + (((size_t)bh * NL + l) << 6);
      #pragma unroll
      for (int nt = 0; nt < 4; ++nt) {
        const int dd = (nt << 4) + (lg << 2);
        bf16x4 o;
        #pragma unroll
        for (int j = 0; j < 4; ++j) o[j] = f2bf(kv[mt][nt][j]);
        *(bf16x4*)(kp + dd) = o;
      }
    }
    #pragma unroll
    for (int nt = 0; nt < 4; ++nt) {
      double p[4];
      #pragma unroll
      for (int j = 0; j < 4; ++j) {
        p[j] = 0.0;
        #pragma unroll
        for (int mt = 0; mt < 4; ++mt) p[j] += (double)kv[mt][nt][j] * inv[mt];
        p[j] += __shfl_xor(p[j], 1);
        p[j] += __shfl_xor(p[j], 2);
        p[j] += __shfl_xor(p[j], 4);
        p[j] += __shfl_xor(p[j], 8);
      }
      if (lr == 0) {
        const int dd = (nt << 4) + (lg << 2);
        double* kp = d.kpart + ((((size_t)bh << 5) + seg) << 6) + dd;
        kp[0] = p[0]; kp[1] = p[1]; kp[2] = p[2]; kp[3] = p[3];
      }
    }
  } else if (d.mode == 3) {
    // ---- fused Q epilogue: q = acc + bias; |q|^2 via shfl; Qbf bf16 + sqv f32
    const int b2 = by >> 4;
    const int hw = (bx << 1) + (wv & 1);
    const int bh = (b2 << 4) + hw;
    #pragma unroll
    for (int mt = 0; mt < 4; ++mt) {
      float kv[4][4];
      float ss = 0.f;
      #pragma unroll
      for (int nt = 0; nt < 4; ++nt) {
        const int n = n0 + wn + (nt << 4) + (lg << 2);
        const float4 b4 = *(const float4*)(d.bias + n);
        kv[nt][0] = acc[mt][nt][0] + b4.x;
        kv[nt][1] = acc[mt][nt][1] + b4.y;
        kv[nt][2] = acc[mt][nt][2] + b4.z;
        kv[nt][3] = acc[mt][nt][3] + b4.w;
        #pragma unroll
        for (int j = 0; j < 4; ++j) ss += kv[nt][j] * kv[nt][j];
      }
      ss += __shfl_xor(ss, 16);
      ss += __shfl_xor(ss, 32);
      const int l = (m0 + wm + (mt << 4) + lr) & (NL - 1);
      if (lg == 0) d.sq[((size_t)bh << 11) + l] = ss;
      short* qp = d.KbfVt + (((size_t)bh * NL + l) << 6);
      #pragma unroll
      for (int nt = 0; nt < 4; ++nt) {
        const int dd = (nt << 4) + (lg << 2);
        bf16x4 o;
        #pragma unroll
        for (int j = 0; j < 4; ++j) o[j] = f2bf(kv[nt][j]);
        *(bf16x4*)(qp + dd) = o;
      }
    }
  } else {
    // ---- fused V epilogue: +bias -> bf16 into LDS T(n,m) (XOR col swizzle),
    //      then coalesced 128B-contiguous stores into Vt[bh][d][l].
    #pragma unroll
    for (int nt = 0; nt < 4; ++nt) {
      const int nl = wn + (nt << 4) + (lg << 2);
      const float4 b4 = *(const float4*)(d.bias + n0 + nl);
      #pragma unroll
      for (int j2 = 0; j2 < 4; ++j2) {
        const int row = nl + j2;
        short* Tp = (row & 64) ? Bs : As;
        const int rr = row & 63;
        const float bj = (j2 == 0) ? b4.x : (j2 == 1) ? b4.y : (j2 == 2) ? b4.z : b4.w;
        const int sw = (row & 7) << 3;
        #pragma unroll
        for (int mt = 0; mt < 4; ++mt) {
          const int m = wm + (mt << 4) + lr;
          Tp[rr * 128 + (m ^ sw)] = f2bf(acc[mt][nt][j2] + bj);
        }
      }
    }
    __syncthreads();
    {
      const int r = tid >> 1, seg2 = tid & 1;
      const short* Tp = (r & 64) ? Bs : As;
      const int rr = r & 63, sw = (r & 7) << 3;
      const int ngl = n0 + r, h = ngl >> 6, dd2 = ngl & 63;
      const int bb = m0 >> 11, ll = m0 & (NL - 1);
      short* dst = d.KbfVt + (((size_t)((((bb << 4) + h) << 6) + dd2)) << 11) + ll + (seg2 << 6);
      #pragma unroll
      for (int i = 0; i < 8; ++i)
        *(bf16x8*)(dst + (i << 3)) =
            *(const bf16x8*)(Tp + rr * 128 + (((seg2 << 6) + (i << 3)) ^ sw));
    }
  }
}

// ---------------------------------------------------------------- wtilde (+inline kbar reduce): wt[bh][j] f32, s0[bh] f64
__global__ __launch_bounds__(256) void wtilde_k(const float* __restrict__ Wq,
                                                const float* __restrict__ bq,
                                                const double* __restrict__ kpart,
                                                float* __restrict__ wt,
                                                double* __restrict__ s0) {
  __shared__ double kb[64];
  const int bh = blockIdx.x, h = bh & 15;
  const int tid = threadIdx.x;
  if (tid < 64) {
    double s = 0.0;
    #pragma unroll
    for (int seg = 0; seg < 32; ++seg)
      s += kpart[((((size_t)bh << 5) + seg) << 6) + tid];
    kb[tid] = s * (1.0 / NL);
  }
  __syncthreads();
  const int j = (blockIdx.y << 8) + tid;
  double a = 0.0;
  #pragma unroll 8
  for (int d = 0; d < 64; ++d)
    a += (double)Wq[(((size_t)((h << 6) + d)) << 10) + j] * kb[d];
  wt[((size_t)bh << 10) + j] = (float)a;
  if (blockIdx.y == 0 && tid < 64) {
    double p = (double)bq[(h << 6) + tid] * kb[tid];
    #pragma unroll
    for (int off = 32; off > 0; off >>= 1) p += __shfl_xor(p, off);
    if (tid == 0) s0[bh] = p;
  }
}

// ---------------------------------------------------------------- fused dotq+msq: ms[bh][l] = (x.wt + s0)/sqrt(sqv)
__global__ __launch_bounds__(256) void dotqms_k(const float* __restrict__ x,
                                                const float* __restrict__ sqv,
                                                const float* __restrict__ wt,
                                                const double* __restrict__ s0,
                                                float* __restrict__ ms) {
  __shared__ float xs[1024];
  __shared__ double sm[16][16];
  const int r = blockIdx.x, b = r >> 11, l = r & (NL - 1);
  const int tid = threadIdx.x;
  ((float4*)xs)[tid] = ((const float4*)(x + ((size_t)r << 10)))[tid];
  __syncthreads();
  const int h = tid >> 4, t = tid & 15;
  const float* w = wt + ((size_t)((b << 4) + h) << 10);
  double a = 0.0;
  #pragma unroll 8
  for (int i = 0; i < 64; ++i) {
    const int j = t + (i << 4);
    a += (double)xs[j] * (double)w[j];
  }
  sm[h][t] = a;
  __syncthreads();
  if (tid < 16) {
    double s = 0.0;
    #pragma unroll
    for (int t2 = 0; t2 < 16; ++t2) s += sm[tid][t2];
    const size_t ro = (((size_t)(b << 4) + tid) << 11) + l;
    ms[ro] = (float)((s + s0[(b << 4) + tid]) / sqrt((double)sqv[ro]));
  }
}

// ---------------------------------------------------------------- rank-based top-NU selection (+ inverse map; pad -> NU)
__global__ __launch_bounds__(256) void select_rank_k(const float* __restrict__ ms,
                                                     int* __restrict__ sel,
                                                     int* __restrict__ invsel) {
  __shared__ unsigned long long keys[NL];
  const int bh = blockIdx.x >> 3, seg = blockIdx.x & 7;
  const int tid = threadIdx.x;
  for (int l = tid; l < NL; l += 256) {
    unsigned u = __float_as_uint(ms[(size_t)bh * NL + l]);
    u = (u & 0x80000000u) ? ~u : (u | 0x80000000u);   // order-preserving map
    keys[l] = ((unsigned long long)u << 32) | (unsigned)(NL - 1 - l);
  }
  __syncthreads();
  const int r = (seg << 8) + tid;
  const unsigned long long mine = keys[r];
  int cnt = 0;
  #pragma unroll 8
  for (int l = 0; l < NL; ++l) cnt += (keys[l] > mine) ? 1 : 0;
  if (cnt < NU) sel[bh*NU + cnt] = r;
  invsel[(size_t)bh * NL + r] = (cnt < NU) ? cnt : NU;  // NU = zeroed pad row
}

// ---------------------------------------------------------------- fused attention; 1024 thr (16 waves, 4/SIMD)
// QK^T: wave w covers n in [w*128,(w+1)*128). Softmax: 2 rows/wave.
// PV: split-K halves; waves 0-7 kh=0, waves 8-15 kh=1 (same (mt,dt) combos);
// kh=1 partials via 8 KB LDS, kh=0 adds + scales + stores Csel.
__global__ __launch_bounds__(1024, 4) void fattn_k(const short* __restrict__ Qbf,
                                                   const int* __restrict__ sel,
                                                   const short* __restrict__ Kbf,
                                                   const short* __restrict__ Vt,
                                                   short* __restrict__ Csel) {
  __shared__ short S[32*2048];        // 128 KB, row stride 4096 B
  __shared__ float pvp[8][64][4];     // 8 KB: kh=1 PV partials
  __shared__ float inv_s[32];
  int bid = blockIdx.x;
  bid = (bid & 7) * 52 + (bid >> 3);  // 416 = 8*52 XCD chunks
  const int m0 = bid << 5;
  const int bh = m0 / NUP;
  const int u0 = m0 - bh * NUP;
  const int tid = threadIdx.x;
  const int w = tid >> 6, L = tid & 63;
  const int lr = L & 15, lg = L >> 4;

  // ---- Q fragments gathered from bf16 Qbf via sel (pad rows read row 0, discarded)
  bf16x8 qf[2][2];
  #pragma unroll
  for (int mt = 0; mt < 2; ++mt) {
    const int u = u0 + mt*16 + lr;
    const int lq = (u < NU) ? sel[bh*NU + u] : 0;
    const short* qp = Qbf + (((size_t)bh*NL + lq) << 6) + lg*8;
    qf[mt][0] = *(const bf16x8*)qp;
    qf[mt][1] = *(const bf16x8*)(qp + 32);
  }
  const int nb = w << 7;              // 128-wide n-range per wave
  const short* kb0 = Kbf + (((size_t)bh*NL + nb + lr) << 6) + lg*8;
  __builtin_amdgcn_s_setprio(1);      // T5
  #pragma unroll 2
  for (int nt = 0; nt < 8; ++nt) {
    const short* kp = kb0 + ((size_t)nt << 10);
    const bf16x8 kf0 = *(const bf16x8*)kp;
    const bf16x8 kf1 = *(const bf16x8*)(kp + 32);
    #pragma unroll
    for (int mt = 0; mt < 2; ++mt) {
      f32x4 a = {0.f,0.f,0.f,0.f};
      a = __builtin_amdgcn_mfma_f32_16x16x32_bf16(kf0, qf[mt][0], a, 0, 0, 0);
      a = __builtin_amdgcn_mfma_f32_16x16x32_bf16(kf1, qf[mt][1], a, 0, 0, 0);
      const int m = mt*16 + lr;
      bf16x4 o;
      #pragma unroll
      for (int r = 0; r < 4; ++r) o[r] = f2bf(a[r] * 0.125f);
      const int byteoff = (m << 12) + ((((nb + nt*16 + lg*4) << 1)) ^ ((m & 7) << 4));
      *(bf16x4*)((char*)S + byteoff) = o;
    }
  }
  __builtin_amdgcn_s_setprio(0);
  __syncthreads();

  // ---- softmax: 2 rows per wave
  #pragma unroll
  for (int j = 0; j < 2; ++j) {
    const int R = (w << 1) + j;
    char* rowp = (char*)S + (R << 12);
    const int sw = (R & 7) << 4;
    bf16x8 v[4];
    #pragma unroll
    for (int i = 0; i < 4; ++i)
      v[i] = *(const bf16x8*)(rowp + (((L << 6) + (i << 4)) ^ sw));
    float f[32];
    #pragma unroll
    for (int i = 0; i < 4; ++i)
      #pragma unroll
      for (int e = 0; e < 8; ++e) f[i*8+e] = bf2f(v[i][e]);
    float mx = f[0];
    #pragma unroll
    for (int i = 1; i < 32; ++i) mx = fmaxf(mx, f[i]);
    #pragma unroll
    for (int off = 32; off > 0; off >>= 1) mx = fmaxf(mx, __shfl_xor(mx, off));
    float sum = 0.f;
    #pragma unroll
    for (int i = 0; i < 32; ++i) { f[i] = __expf(f[i] - mx); sum += f[i]; }
    #pragma unroll
    for (int off = 32; off > 0; off >>= 1) sum += __shfl_xor(sum, off);
    bf16x8 p[4];
    #pragma unroll
    for (int i = 0; i < 4; ++i)
      #pragma unroll
      for (int e = 0; e < 8; ++e) p[i][e] = f2bf(f[i*8+e]);
    #pragma unroll
    for (int i = 0; i < 4; ++i)
      *(bf16x8*)(rowp + (((L << 6) + (i << 4)) ^ sw)) = p[i];
    if (L == 0) inv_s[R] = 1.f / sum;
  }
  __syncthreads();

  // ---- PV: split-K halves across wave groups
  {
    const int mt = w & 1, dt = (w >> 1) & 3, kh = w >> 3;
    const int m = mt*16 + lr;
    const char* arow = (const char*)S + (m << 12);
    const int sw = (m & 7) << 4;
    const short* vrow = Vt + (((size_t)bh*ND + dt*16 + lr) << 11) + (kh << 10) + lg*8;
    const int kbase = kh << 10;
    f32x4 acc0 = {0.f,0.f,0.f,0.f}, acc1 = {0.f,0.f,0.f,0.f};
    __builtin_amdgcn_s_setprio(1);    // T5
    #pragma unroll 2
    for (int k0 = 0; k0 < 1024; k0 += 64) {
      const bf16x8 p0 = *(const bf16x8*)(arow + ((((kbase + k0 + lg*8) << 1)) ^ sw));
      const bf16x8 p1 = *(const bf16x8*)(arow + ((((kbase + k0 + 32 + lg*8) << 1)) ^ sw));
      const bf16x8 v0 = *(const bf16x8*)(vrow + k0);
      const bf16x8 v1 = *(const bf16x8*)(vrow + k0 + 32);
      acc0 = __builtin_amdgcn_mfma_f32_16x16x32_bf16(p0, v0, acc0, 0, 0, 0);
      acc1 = __builtin_amdgcn_mfma_f32_16x16x32_bf16(p1, v1, acc1, 0, 0, 0);
    }
    __builtin_amdgcn_s_setprio(0);
    if (kh == 1) {
      #pragma unroll
      for (int r = 0; r < 4; ++r) pvp[w & 7][L][r] = acc0[r] + acc1[r];
    }
    __syncthreads();
    if (kh == 0) {
      const int ub = u0 + mt*16 + (lg << 2);
      #pragma unroll
      for (int r = 0; r < 4; ++r) {
        float val = (acc0[r] + acc1[r] + pvp[w][L][r]) * inv_s[mt*16 + (lg << 2) + r];
        if (ub + r >= NU) val = 0.f;               // zero pad rows (incl. row NU)
        const size_t off = (((size_t)m0 + mt*16 + (lg << 2) + r) << 6) + dt*16 + lr;
        Csel[off] = f2bf(val);
      }
    }
  }
}

// ---------------------------------------------------------------- O projection GEMM (X gathered from Csel via invsel)
// Single W chunk (Wo bf16), 16 steps. 64x128 tiles, 512 blocks, bias fused,
// writes out directly. Operands (Csel 1.6MB, Wobf 2MB, invsel 1MB) L2-resident.
struct OselArgs {
  const short* X;
  const short* W;
  const float* bias;
  float* C;
  const int* invsel;
};

__global__ __launch_bounds__(256, 3) void gemm_osel_k(OselArgs ar) {
  __shared__ short As[64*64];    // 8 KB
  __shared__ short Bs[128*64];   // 16 KB
  __shared__ int utbl[1024];     // 4 KB
  const int fid = blockIdx.x;               // 0..511
  const int xcd = fid & 7, jj = fid >> 3;   // jj 0..63
  const int o = (xcd << 6) + jj;            // 0..511, XCD-chunked
  const int bx = o & 7, by = o >> 3;        // bx 0..7, by 0..63
  const int tid = threadIdx.x;
  const int wv = tid >> 6, L = tid & 63;
  const int lr = L & 15, lg = L >> 4;
  const int n0 = bx << 7, m0 = by << 6;
  const int wm = (wv >> 1) << 5, wn = (wv & 1) << 6;
  const int sr = tid >> 3, ssl = tid & 7;
  const int b2 = by >> 5;                   // batch

  #pragma unroll
  for (int e = 0; e < 4; ++e) {
    const int idx = (tid << 2) + e;             // 0..1023
    const int row = idx >> 4, h = idx & 15;
    utbl[idx] = ar.invsel[((((size_t)b2 << 4) + h) << 11) + ((m0 + row) & (NL - 1))];
  }
  __syncthreads();

  f32x4 acc[2][4];
  #pragma unroll
  for (int i = 0; i < 2; ++i)
    #pragma unroll
    for (int j = 0; j < 4; ++j) acc[i][j] = (f32x4){0.f,0.f,0.f,0.f};

  for (int step = 0; step < 16; ++step) {
    const int kk = step << 6;
    #pragma unroll
    for (int j = 0; j < 2; ++j) {
      const int row = (j << 5) + sr;
      const int slot = (ssl ^ (row & 7)) << 3;
      const int h = step & 15;                  // one head per 64-wide step
      const int u = utbl[(row << 4) + h];
      gload16(ar.X + (((size_t)((b2 << 4) + h) * NUP + u) << 6) + slot,
              As + (j << 11) + (tid << 3));
    }
    #pragma unroll
    for (int j = 0; j < 4; ++j) {
      const int row = (j << 5) + sr;
      const int slot = (ssl ^ (row & 7)) << 3;
      gload16(ar.W + (size_t)(n0 + row) * NDM + kk + slot, Bs + (j << 11) + (tid << 3));
    }
    __syncthreads();
    #pragma unroll
    for (int c2 = 0; c2 < 2; ++c2) {
      const int sl = (((c2 << 2) + lg) ^ (lr & 7)) << 3;
      bf16x8 af[2], bfr[4];
      #pragma unroll
      for (int t = 0; t < 2; ++t)
        af[t] = *(const bf16x8*)(As + ((wm + (t << 4) + lr) << 6) + sl);
      #pragma unroll
      for (int t = 0; t < 4; ++t)
        bfr[t] = *(const bf16x8*)(Bs + ((wn + (t << 4) + lr) << 6) + sl);
      #pragma unroll
      for (int mt = 0; mt < 2; ++mt)
        #pragma unroll
        for (int nt = 0; nt < 4; ++nt)
          acc[mt][nt] = __builtin_amdgcn_mfma_f32_16x16x32_bf16(bfr[nt], af[mt], acc[mt][nt], 0, 0, 0);
    }
    __syncthreads();
  }

  #pragma unroll
  for (int nt = 0; nt < 4; ++nt) {
    const int n = n0 + wn + (nt << 4) + (lg << 2);
    const float4 b4 = *(const float4*)(ar.bias + n);
    #pragma unroll
    for (int mt = 0; mt < 2; ++mt) {
      f32x4 a = acc[mt][nt];
      a[0] += b4.x; a[1] += b4.y; a[2] += b4.z; a[3] += b4.w;
      const int m = m0 + wm + (mt << 4) + lr;
      *(f32x4*)(ar.C + ((size_t)m << 10) + n) = a;
    }
  }
}

// ---------------------------------------------------------------- launch
extern "C" void kernel_launch(void* const* d_in, const int* in_sizes, int n_in,
                              void* d_out, int out_size, void* d_ws, size_t ws_size,
                              hipStream_t stream)
{
  (void)in_sizes; (void)n_in; (void)out_size; (void)ws_size;
  const float* queries = (const float*)d_in[0];
  const float* keys    = (const float*)d_in[1];
  const float* values  = (const float*)d_in[2];
  const float* Wq = (const float*)d_in[3];  const float* bq = (const float*)d_in[4];
  const float* Wk = (const float*)d_in[5];  const float* bk = (const float*)d_in[6];
  const float* Wv = (const float*)d_in[7];  const float* bv = (const float*)d_in[8];
  const float* Wo = (const float*)d_in[9];  const float* bo = (const float*)d_in[10];
  float* out = (float*)d_out;

  char* base = (char*)d_ws;
  #define MB(x) ((size_t)(x) << 20)

  short* Qa   = (short*)(base + MB(0));    // queries split a (dead after mega)
  short* Qb2  = (short*)(base + MB(8));    // queries split b
  short* Ka   = (short*)(base + MB(16));   // keys split a (dead after mega)
  short* Kb2  = (short*)(base + MB(24));
  short* Kbf  = (short*)(base + MB(32));   // written by mega K epilogue
  short* Vbf  = (short*)(base + MB(40));   // -> Csel after mega
  short* Qbf  = (short*)(base + MB(48));   // written by mega Q epilogue
  short* Vt   = (short*)(base + MB(56));   // written by mega V epilogue
  short* Wqa  = (short*)(base + MB(64));
  short* Wqb  = (short*)(base + MB(66));
  short* Wka  = (short*)(base + MB(68));
  short* Wkb  = (short*)(base + MB(70));
  short* Wvbf = (short*)(base + MB(72));
  short* Wobf = (short*)(base + MB(74));
  char* sm = base + MB(78);
  double* kpart  = (double*)sm;  sm += 524288;    // [32][32][64] f64
  float*  wt     = (float*)sm;   sm += 131072;    // [32][1024] f32
  double* s0     = (double*)sm;  sm += 512;
  float*  sqv    = (float*)sm;   sm += 262144;    // [32][2048] f32
  float*  msb    = (float*)sm;   sm += 262144;
  int*    sel    = (int*)sm;     sm += 65536;
  int*    invsel = (int*)sm;     sm += 262144;

  // time-multiplexed aliases
  short* Csel = Vbf;                        // 1.625 MiB, after mega

  // ---- 1: all splits in one launch (inputs + weights)
  {
    SplitArgs a;
    a.d[0] = {queries, Qa, Qb2, nullptr, 2, 2048};
    a.d[1] = {keys,    Ka, Kb2, nullptr, 2, 2048};
    a.d[2] = {values,  Vbf, nullptr, nullptr, 1, 2048};
    a.d[3] = {Wq, Wqa, Wqb, nullptr, 2, 512};
    a.d[4] = {Wk, Wka, Wkb, nullptr, 2, 512};
    a.d[5] = {Wv, Wvbf, nullptr, nullptr, 1, 512};
    a.d[6] = {Wo, Wobf, nullptr, nullptr, 1, 512};
    msplit_k<<<dim3(2048,1,7), 256, 0, stream>>>(a);
  }
  // ---- 2: balanced mega GEMM, full tiles: Q(48, fused bf16+|q|^2 epilogue)
  //         + K(48, fused norm/kbar) + V(16, fused transpose); 768 blocks
  {
    GemmArgs g;
    g.d[0] = {{Qa,Qb2},  {Wqa,Wqb},   bq, Qbf, nullptr, sqv,     0, 48, 3};
    g.d[1] = {{Ka,Kb2},  {Wka,Wkb},   bk, Kbf, kpart,   nullptr, 0, 48, 1};
    g.d[2] = {{Vbf,Vbf}, {Wvbf,Wvbf}, bv, Vt,  nullptr, nullptr, 0, 16, 2};
    gemm_mega_k<<<768, 256, 0, stream>>>(g);
  }
  // ---- 3-5: ranking chain
  wtilde_k<<<dim3(NBH,4), 256, 0, stream>>>(Wq, bq, kpart, wt, s0);
  dotqms_k<<<NROWS, 256, 0, stream>>>(queries, sqv, wt, s0, msb);
  select_rank_k<<<NBH*8, 256, 0, stream>>>(msb, sel, invsel);

  // ---- 6: fused attention (1024 thr, split-K PV; single bf16 Csel)
  fattn_k<<<MTOT/32, 1024, 0, stream>>>(Qbf, sel, Kbf, Vt, Csel);

  // ---- 7: output projection, single Wo chunk, bias fused; writes out directly
  {
    OselArgs oa = {Csel, Wobf, bo, out, invsel};
    gemm_osel_k<<<512, 256, 0, stream>>>(oa);
  }
}